// Round 1
// baseline (2729.253 us; speedup 1.0000x reference)
//
#include <hip/hip_runtime.h>
#include <math.h>

#define L_TOKN 13294
#define BATCHN 4
#define NTOK (BATCHN * L_TOKN)   // 53176
#define DMODEL 256
#define DFFN 1024

#define BM 64
#define BN 64
#define BK 16

// ---------------------------------------------------------------------------
// Generic tiled f32 GEMM: C[M,N] = (A1 (+A2)) [M,K] @ W[K,N] + bias[N], opt ReLU
// 256 threads, 64x64 tile, 4x4 per-thread micro-tile.
// ---------------------------------------------------------------------------
__global__ __launch_bounds__(256) void gemm_k(
    const float* __restrict__ A1, const float* __restrict__ A2,
    const float* __restrict__ W, const float* __restrict__ bias,
    float* __restrict__ C, int M, int N, int K, int relu)
{
    __shared__ float As[BK][BM + 4];   // +4 pad keeps 16B alignment, breaks bank stride
    __shared__ float Bs[BK][BN];

    const int m0 = blockIdx.x * BM;
    const int n0 = blockIdx.y * BN;
    const int t  = threadIdx.x;
    const int tr = t >> 4;     // 0..15
    const int tc = t & 15;     // 0..15

    float acc[4][4] = {};

    for (int k0 = 0; k0 < K; k0 += BK) {
        // A tile 64x16, coalesced over k, stored transposed As[k][m]
        #pragma unroll
        for (int i = 0; i < 4; i++) {
            int flat = t + i * 256;
            int r = flat >> 4;        // m within tile
            int c = flat & 15;        // k within tile
            int gm = m0 + r;
            float v = 0.f;
            if (gm < M) {
                size_t gi = (size_t)gm * K + (k0 + c);
                v = A1[gi];
                if (A2) v += A2[gi];
            }
            As[c][r] = v;
        }
        // B tile 16x64, coalesced over n
        #pragma unroll
        for (int i = 0; i < 4; i++) {
            int flat = t + i * 256;
            int r = flat >> 6;        // k within tile
            int c = flat & 63;        // n within tile
            Bs[r][c] = W[(size_t)(k0 + r) * N + (n0 + c)];
        }
        __syncthreads();
        #pragma unroll
        for (int kk = 0; kk < BK; kk++) {
            float4 a = *(const float4*)&As[kk][tr * 4];
            float4 b = *(const float4*)&Bs[kk][tc * 4];
            acc[0][0] += a.x * b.x; acc[0][1] += a.x * b.y; acc[0][2] += a.x * b.z; acc[0][3] += a.x * b.w;
            acc[1][0] += a.y * b.x; acc[1][1] += a.y * b.y; acc[1][2] += a.y * b.z; acc[1][3] += a.y * b.w;
            acc[2][0] += a.z * b.x; acc[2][1] += a.z * b.y; acc[2][2] += a.z * b.z; acc[2][3] += a.z * b.w;
            acc[3][0] += a.w * b.x; acc[3][1] += a.w * b.y; acc[3][2] += a.w * b.z; acc[3][3] += a.w * b.w;
        }
        __syncthreads();
    }

    #pragma unroll
    for (int i = 0; i < 4; i++) {
        int row = m0 + tr * 4 + i;
        if (row >= M) continue;
        #pragma unroll
        for (int j = 0; j < 4; j++) {
            int col = n0 + tc * 4 + j;
            float v = acc[i][j] + bias[col];
            if (relu) v = fmaxf(v, 0.f);
            C[(size_t)row * N + col] = v;
        }
    }
}

// ---------------------------------------------------------------------------
// Deformable attention core. One block per token (b,l). 256 threads = (h, d).
// Reads raw offset proj + raw aw logits, does per-head softmax(16) in LDS,
// bilinear-gathers value, writes acc (B,L,H*32) to OUT.
// ---------------------------------------------------------------------------
__global__ __launch_bounds__(256) void deform_k(
    const float* __restrict__ V,     // (NTOK, 256) = (b,l, h*32+d)
    const float* __restrict__ OFF,   // (NTOK, 256) = h*32 + lvl*8 + p*2 + xy
    const float* __restrict__ AWL,   // (NTOK, 128) = h*16 + lvl*4 + p
    float* __restrict__ OUT)         // (NTOK, 256)
{
    __shared__ float offs_s[256];
    __shared__ float aw_s[128];

    const int row = blockIdx.x;
    const int t = threadIdx.x;

    offs_s[t] = OFF[(size_t)row * 256 + t];
    if (t < 128) aw_s[t] = AWL[(size_t)row * 128 + t];
    __syncthreads();

    if (t < 8) {   // softmax over 16 per head
        float mx = -1e30f;
        #pragma unroll
        for (int i = 0; i < 16; i++) mx = fmaxf(mx, aw_s[t * 16 + i]);
        float e[16]; float sm = 0.f;
        #pragma unroll
        for (int i = 0; i < 16; i++) { e[i] = __expf(aw_s[t * 16 + i] - mx); sm += e[i]; }
        float inv = 1.f / sm;
        #pragma unroll
        for (int i = 0; i < 16; i++) aw_s[t * 16 + i] = e[i] * inv;
    }
    __syncthreads();

    const int b = row / L_TOKN;
    const int l = row - b * L_TOKN;

    // reference point for this token (levels are square: H == W)
    int st_q, Wq;
    if      (l < 10000) { st_q = 0;     Wq = 100; }
    else if (l < 12500) { st_q = 10000; Wq = 50;  }
    else if (l < 13125) { st_q = 12500; Wq = 25;  }
    else                { st_q = 13125; Wq = 13;  }
    const int li = l - st_q;
    const int rowi = li / Wq;
    const int coli = li - rowi * Wq;
    const float rx = (coli + 0.5f) / (float)Wq;
    const float ry = (rowi + 0.5f) / (float)Wq;

    const int h = t >> 5;
    const int d = t & 31;

    const int HW[4] = {100, 50, 25, 13};
    const int ST[4] = {0, 10000, 12500, 13125};

    float acc = 0.f;
    const float* Vbh = V + (size_t)b * L_TOKN * 256 + h * 32 + d;

    #pragma unroll
    for (int lv = 0; lv < 4; lv++) {
        const int   Wl  = HW[lv];
        const float Wlf = (float)Wl;
        const int   stl = ST[lv];
        #pragma unroll
        for (int p = 0; p < 4; p++) {
            float ox = offs_s[h * 32 + lv * 8 + p * 2 + 0];
            float oy = offs_s[h * 32 + lv * 8 + p * 2 + 1];
            float x = (rx + ox / Wlf) * Wlf - 0.5f;
            float y = (ry + oy / Wlf) * Wlf - 0.5f;
            float x0f = floorf(x), y0f = floorf(y);
            float wx1 = x - x0f, wy1 = y - y0f;
            int x0 = (int)x0f, y0 = (int)y0f;
            float aw = aw_s[h * 16 + lv * 4 + p];
            float w00 = (1.f - wx1) * (1.f - wy1) * aw;
            float w10 = wx1 * (1.f - wy1) * aw;
            float w01 = (1.f - wx1) * wy1 * aw;
            float w11 = wx1 * wy1 * aw;
            bool xin0 = (x0 >= 0) && (x0 < Wl);
            bool xin1 = (x0 + 1 >= 0) && (x0 + 1 < Wl);
            if (y0 >= 0 && y0 < Wl) {
                const float* vr = Vbh + (size_t)(stl + y0 * Wl) * 256;
                if (xin0) acc += w00 * vr[(size_t)x0 * 256];
                if (xin1) acc += w10 * vr[(size_t)(x0 + 1) * 256];
            }
            if (y0 + 1 >= 0 && y0 + 1 < Wl) {
                const float* vr = Vbh + (size_t)(stl + (y0 + 1) * Wl) * 256;
                if (xin0) acc += w01 * vr[(size_t)x0 * 256];
                if (xin1) acc += w11 * vr[(size_t)(x0 + 1) * 256];
            }
        }
    }
    OUT[(size_t)row * 256 + t] = acc;
}

// ---------------------------------------------------------------------------
// LayerNorm over 256 with fused residual: out = LN(in1 (+in2)) * g + b
// One block per token, 256 threads.
// ---------------------------------------------------------------------------
__global__ __launch_bounds__(256) void ln_k(
    const float* __restrict__ in1, const float* __restrict__ in2,
    const float* __restrict__ g, const float* __restrict__ bta,
    float* __restrict__ out)
{
    const int row = blockIdx.x;
    const int t = threadIdx.x;
    float v = in1[(size_t)row * 256 + t];
    if (in2) v += in2[(size_t)row * 256 + t];

    __shared__ float red[4];
    __shared__ float mu_s, rstd_s;
    const int wid = t >> 6, lane = t & 63;

    float s = v;
    #pragma unroll
    for (int o = 32; o; o >>= 1) s += __shfl_xor(s, o);
    if (lane == 0) red[wid] = s;
    __syncthreads();
    if (t == 0) mu_s = (red[0] + red[1] + red[2] + red[3]) * (1.f / 256.f);
    __syncthreads();
    const float mu = mu_s;
    const float dv = v - mu;
    float s2 = dv * dv;
    #pragma unroll
    for (int o = 32; o; o >>= 1) s2 += __shfl_xor(s2, o);
    if (lane == 0) red[wid] = s2;
    __syncthreads();
    if (t == 0) rstd_s = rsqrtf((red[0] + red[1] + red[2] + red[3]) * (1.f / 256.f) + 1e-5f);
    __syncthreads();
    out[(size_t)row * 256 + t] = dv * rstd_s * g[t] + bta[t];
}

// ---------------------------------------------------------------------------
extern "C" void kernel_launch(void* const* d_in, const int* in_sizes, int n_in,
                              void* d_out, int out_size, void* d_ws, size_t ws_size,
                              hipStream_t stream)
{
    const float* src     = (const float*)d_in[0];
    const float* src2    = (const float*)d_in[1];
    const float* pos     = (const float*)d_in[2];
    const float* mpos    = (const float*)d_in[3];
    const float* value_w = (const float*)d_in[4];
    const float* value_b = (const float*)d_in[5];
    const float* off_w   = (const float*)d_in[6];
    const float* off_b   = (const float*)d_in[7];
    const float* aw_w    = (const float*)d_in[8];
    const float* aw_b    = (const float*)d_in[9];
    const float* out_w   = (const float*)d_in[10];
    const float* out_b   = (const float*)d_in[11];
    const float* ln_g    = (const float*)d_in[12];
    const float* ln_b    = (const float*)d_in[13];
    const float* lin1_w  = (const float*)d_in[14];
    const float* lin1_b  = (const float*)d_in[15];
    const float* lin2_w  = (const float*)d_in[16];
    const float* lin2_b  = (const float*)d_in[17];

    float* outp = (float*)d_out;
    float* ws   = (float*)d_ws;

    const size_t E = (size_t)NTOK * DMODEL;   // 13,613,056
    float* bufV = ws;                 // value                    (E)
    float* bufO = bufV + E;           // off raw / attn out       (E)
    float* bufA = bufO + E;           // aw logits                (E/2)
    float* bufX = bufA + E / 2;       // x after LN1              (E)
    float* bufH = bufX + E;           // ffn hidden chunk         (4096*1024)

    const dim3 blk(256);
    const int mt = (NTOK + BM - 1) / BM;   // 831

    // 1-3: input projections (fused q = src+pos, mem = src2+mpos)
    gemm_k<<<dim3(mt, 4), blk, 0, stream>>>(src2, mpos, value_w, value_b, bufV, NTOK, 256, 256, 0);
    gemm_k<<<dim3(mt, 4), blk, 0, stream>>>(src,  pos,  off_w,   off_b,   bufO, NTOK, 256, 256, 0);
    gemm_k<<<dim3(mt, 2), blk, 0, stream>>>(src,  pos,  aw_w,    aw_b,    bufA, NTOK, 128, 256, 0);

    // 4: deformable attention core -> acc staged in d_out (overwritten later)
    deform_k<<<dim3(NTOK), blk, 0, stream>>>(bufV, bufO, bufA, outp);

    // 5: output projection (reuse bufO)
    gemm_k<<<dim3(mt, 4), blk, 0, stream>>>(outp, nullptr, out_w, out_b, bufO, NTOK, 256, 256, 0);

    // 6: x = LN(src + attn)
    ln_k<<<dim3(NTOK), blk, 0, stream>>>(bufO, src, ln_g, ln_b, bufX);

    // 7-8: FFN, chunked so hidden stays small (reuse bufV for y = ffn2 out)
    const int CH = 4096;
    for (int c0 = 0; c0 < NTOK; c0 += CH) {
        int mr = NTOK - c0; if (mr > CH) mr = CH;
        int cmt = (mr + BM - 1) / BM;
        gemm_k<<<dim3(cmt, 16), blk, 0, stream>>>(bufX + (size_t)c0 * DMODEL, nullptr,
                                                  lin1_w, lin1_b, bufH, mr, DFFN, DMODEL, 1);
        gemm_k<<<dim3(cmt, 4), blk, 0, stream>>>(bufH, nullptr,
                                                 lin2_w, lin2_b, bufV + (size_t)c0 * DMODEL, mr, DMODEL, DFFN, 0);
    }

    // 9: out = LN(x + ffn)
    ln_k<<<dim3(NTOK), blk, 0, stream>>>(bufV, bufX, ln_g, ln_b, outp);
}

// Round 2
// 788.175 us; speedup vs baseline: 3.4628x; 3.4628x over previous
//
#include <hip/hip_runtime.h>
#include <math.h>

#define L_TOKN 13294
#define BATCHN 4
#define NTOK (BATCHN * L_TOKN)   // 53176
#define DMODEL 256
#define DFFN 1024

typedef __attribute__((ext_vector_type(8))) short short8;
typedef __attribute__((ext_vector_type(4))) float f32x4;

__device__ __forceinline__ ushort f2b(float f) {
    uint u = __float_as_uint(f);
    u += 0x7fff + ((u >> 16) & 1);           // round-to-nearest-even
    return (ushort)(u >> 16);
}
__device__ __forceinline__ float b2f(ushort h) {
    return __uint_as_float(((uint)h) << 16);
}

// ---------------------------------------------------------------------------
// addcvt: out_bf16 = bf16(a + b), vectorized float4
// ---------------------------------------------------------------------------
__global__ __launch_bounds__(256) void addcvt_k(
    const float* __restrict__ a, const float* __restrict__ b,
    ushort* __restrict__ o, int n4)
{
    int i = blockIdx.x * 256 + threadIdx.x;
    if (i >= n4) return;
    float4 va = ((const float4*)a)[i];
    float4 vb = ((const float4*)b)[i];
    ushort4 r;
    r.x = f2b(va.x + vb.x); r.y = f2b(va.y + vb.y);
    r.z = f2b(va.z + vb.z); r.w = f2b(va.w + vb.w);
    ((ushort4*)o)[i] = r;
}

// ---------------------------------------------------------------------------
// weight transpose+convert: W[K][N] f32 -> Wt[N][K] bf16
// ---------------------------------------------------------------------------
__global__ __launch_bounds__(256) void wtrans_k(
    const float* __restrict__ w, ushort* __restrict__ wt, int Kd, int Nd)
{
    int i = blockIdx.x * 256 + threadIdx.x;
    if (i >= Kd * Nd) return;
    int k = i / Nd, n = i - k * Nd;
    wt[(size_t)n * Kd + k] = f2b(w[i]);
}

// ---------------------------------------------------------------------------
// bf16 MFMA GEMM: C[M,N] = A[M,K](bf16) @ Wt[N,K]^T(bf16) + bias
// 256 threads, 128x128 tile, BK=32, 4 waves each 64x64 (4x4 frags of 16x16).
// Writes f32 (Cf) and/or bf16 (Cb). Optional ReLU.
// ---------------------------------------------------------------------------
__global__ __launch_bounds__(256) void mgemm_k(
    const ushort* __restrict__ A, const ushort* __restrict__ Wt,
    const float* __restrict__ bias,
    float* __restrict__ Cf, ushort* __restrict__ Cb,
    int M, int N, int K, int relu)
{
    __shared__ ushort As[128 * 40];   // [m][k] pad 32->40 (80B rows, 16B aligned)
    __shared__ ushort Bs[128 * 40];   // [n][k]

    const int t  = threadIdx.x;
    const int m0 = blockIdx.x * 128;
    const int n0 = blockIdx.y * 128;

    const int r    = t >> 1;          // staging row 0..127
    const int hseg = t & 1;           // 16-elem half of the 32-k slice

    const int lane = t & 63, w = t >> 6;
    const int wr = w >> 1, wc = w & 1;
    const int fr = lane & 15;         // frag row/col
    const int kg = lane >> 4;         // k-group (8 elems each)

    f32x4 acc[4][4];
    #pragma unroll
    for (int i = 0; i < 4; i++)
        #pragma unroll
        for (int j = 0; j < 4; j++) acc[i][j] = (f32x4)0.0f;

    // loop-invariant LDS fragment addresses
    const ushort* apt[4];
    const ushort* bpt[4];
    #pragma unroll
    for (int i = 0; i < 4; i++) {
        apt[i] = &As[(wr * 64 + i * 16 + fr) * 40 + kg * 8];
        bpt[i] = &Bs[(wc * 64 + i * 16 + fr) * 40 + kg * 8];
    }

    const int nk = K >> 5;
    for (int ks = 0; ks < nk; ks++) {
        const int k0 = ks << 5;
        // stage A (128x32 bf16): 2x16B load + 2 ds_write_b128 per thread
        {
            int gm = m0 + r;
            uint4 v0 = {0, 0, 0, 0}, v1 = {0, 0, 0, 0};
            if (gm < M) {
                const ushort* ap = A + (size_t)gm * K + k0 + hseg * 16;
                v0 = *(const uint4*)ap;
                v1 = *(const uint4*)(ap + 8);
            }
            *(uint4*)&As[r * 40 + hseg * 16]     = v0;
            *(uint4*)&As[r * 40 + hseg * 16 + 8] = v1;
            const ushort* bp = Wt + (size_t)(n0 + r) * K + k0 + hseg * 16;
            uint4 w0 = *(const uint4*)bp;
            uint4 w1 = *(const uint4*)(bp + 8);
            *(uint4*)&Bs[r * 40 + hseg * 16]     = w0;
            *(uint4*)&Bs[r * 40 + hseg * 16 + 8] = w1;
        }
        __syncthreads();
        short8 af[4], bfr[4];
        #pragma unroll
        for (int i = 0; i < 4; i++) {
            af[i]  = *(const short8*)apt[i];
            bfr[i] = *(const short8*)bpt[i];
        }
        #pragma unroll
        for (int i = 0; i < 4; i++)
            #pragma unroll
            for (int j = 0; j < 4; j++)
                acc[i][j] = __builtin_amdgcn_mfma_f32_16x16x32_bf16(af[i], bfr[j], acc[i][j], 0, 0, 0);
        __syncthreads();
    }

    // epilogue: D[row=(lane>>4)*4+e][col=lane&15] per frag
    #pragma unroll
    for (int i = 0; i < 4; i++) {
        #pragma unroll
        for (int j = 0; j < 4; j++) {
            int col = n0 + wc * 64 + j * 16 + fr;
            float bv = bias[col];
            #pragma unroll
            for (int e = 0; e < 4; e++) {
                int row = m0 + wr * 64 + i * 16 + kg * 4 + e;
                if (row < M) {
                    float v = acc[i][j][e] + bv;
                    if (relu) v = fmaxf(v, 0.f);
                    if (Cf) Cf[(size_t)row * N + col] = v;
                    if (Cb) Cb[(size_t)row * N + col] = f2b(v);
                }
            }
        }
    }
}

// ---------------------------------------------------------------------------
// Deformable attention core. 4 tokens/block, 64 threads/token = 8 heads x 8.
// Each thread owns 4 channels -> ushort4 (8B) bf16 gather loads.
// ---------------------------------------------------------------------------
__global__ __launch_bounds__(256) void deform_k(
    const ushort* __restrict__ Vb,   // bf16 (NTOK,256)
    const float* __restrict__ OFF,   // f32  (NTOK,256): h*32 + lv*8 + p*2 + xy
    const float* __restrict__ AWL,   // f32  (NTOK,128): h*16 + lv*4 + p
    ushort* __restrict__ OUTb)       // bf16 (NTOK,256)
{
    __shared__ float offs_s[4][256];
    __shared__ float aw_s[4][128];

    const int t  = threadIdx.x;
    const int ti = t >> 6;           // token within block
    const int tt = t & 63;           // thread within token
    const int row = blockIdx.x * 4 + ti;

    const float* op = OFF + (size_t)row * 256;
    offs_s[ti][tt]       = op[tt];
    offs_s[ti][tt + 64]  = op[tt + 64];
    offs_s[ti][tt + 128] = op[tt + 128];
    offs_s[ti][tt + 192] = op[tt + 192];
    const float* apx = AWL + (size_t)row * 128;
    aw_s[ti][tt]      = apx[tt];
    aw_s[ti][tt + 64] = apx[tt + 64];
    __syncthreads();

    if (tt < 8) {   // per-head softmax over 16
        float* a = &aw_s[ti][tt * 16];
        float mx = -1e30f;
        #pragma unroll
        for (int i = 0; i < 16; i++) mx = fmaxf(mx, a[i]);
        float e[16]; float sm = 0.f;
        #pragma unroll
        for (int i = 0; i < 16; i++) { e[i] = __expf(a[i] - mx); sm += e[i]; }
        float inv = 1.f / sm;
        #pragma unroll
        for (int i = 0; i < 16; i++) a[i] = e[i] * inv;
    }
    __syncthreads();

    const int b = row / L_TOKN;
    const int l = row - b * L_TOKN;

    int st_q, Wq;
    if      (l < 10000) { st_q = 0;     Wq = 100; }
    else if (l < 12500) { st_q = 10000; Wq = 50;  }
    else if (l < 13125) { st_q = 12500; Wq = 25;  }
    else                { st_q = 13125; Wq = 13;  }
    const int li = l - st_q;
    const int rowi = li / Wq;
    const int coli = li - rowi * Wq;
    const float rx = (coli + 0.5f) / (float)Wq;
    const float ry = (rowi + 0.5f) / (float)Wq;

    const int h  = tt >> 3;
    const int dq = tt & 7;
    const float* offh = &offs_s[ti][h * 32];
    const float* awh  = &aw_s[ti][h * 16];
    const ushort* Vbh = Vb + (size_t)b * L_TOKN * 256 + h * 32 + dq * 4;

    const int HWc[4] = {100, 50, 25, 13};
    const int STc[4] = {0, 10000, 12500, 13125};

    float a0 = 0.f, a1 = 0.f, a2 = 0.f, a3 = 0.f;

    #pragma unroll
    for (int lv = 0; lv < 4; lv++) {
        const int   Wl  = HWc[lv];
        const float Wlf = (float)Wl;
        const int   stl = STc[lv];
        #pragma unroll
        for (int p = 0; p < 4; p++) {
            float ox = offh[lv * 8 + p * 2 + 0];
            float oy = offh[lv * 8 + p * 2 + 1];
            float lx = rx + ox / Wlf, ly = ry + oy / Wlf;
            float x = lx * Wlf - 0.5f, y = ly * Wlf - 0.5f;
            float x0f = floorf(x), y0f = floorf(y);
            float wx1 = x - x0f, wy1 = y - y0f;
            int x0 = (int)x0f, y0 = (int)y0f;
            float aw = awh[lv * 4 + p];
            float w00 = (1.f - wx1) * (1.f - wy1) * aw;
            float w10 = wx1 * (1.f - wy1) * aw;
            float w01 = (1.f - wx1) * wy1 * aw;
            float w11 = wx1 * wy1 * aw;
            bool xin0 = (x0 >= 0) && (x0 < Wl);
            bool xin1 = (x0 + 1 >= 0) && (x0 + 1 < Wl);
            if (y0 >= 0 && y0 < Wl) {
                const ushort* vr = Vbh + (size_t)(stl + y0 * Wl) * 256;
                if (xin0) {
                    ushort4 u = *(const ushort4*)(vr + (size_t)x0 * 256);
                    a0 += w00 * b2f(u.x); a1 += w00 * b2f(u.y);
                    a2 += w00 * b2f(u.z); a3 += w00 * b2f(u.w);
                }
                if (xin1) {
                    ushort4 u = *(const ushort4*)(vr + (size_t)(x0 + 1) * 256);
                    a0 += w10 * b2f(u.x); a1 += w10 * b2f(u.y);
                    a2 += w10 * b2f(u.z); a3 += w10 * b2f(u.w);
                }
            }
            if (y0 + 1 >= 0 && y0 + 1 < Wl) {
                const ushort* vr = Vbh + (size_t)(stl + (y0 + 1) * Wl) * 256;
                if (xin0) {
                    ushort4 u = *(const ushort4*)(vr + (size_t)x0 * 256);
                    a0 += w01 * b2f(u.x); a1 += w01 * b2f(u.y);
                    a2 += w01 * b2f(u.z); a3 += w01 * b2f(u.w);
                }
                if (xin1) {
                    ushort4 u = *(const ushort4*)(vr + (size_t)(x0 + 1) * 256);
                    a0 += w11 * b2f(u.x); a1 += w11 * b2f(u.y);
                    a2 += w11 * b2f(u.z); a3 += w11 * b2f(u.w);
                }
            }
        }
    }
    ushort4 o;
    o.x = f2b(a0); o.y = f2b(a1); o.z = f2b(a2); o.w = f2b(a3);
    *(ushort4*)(OUTb + (size_t)row * 256 + h * 32 + dq * 4) = o;
}

// ---------------------------------------------------------------------------
// LayerNorm(256) fused residual; writes f32 out and optional bf16 copy
// ---------------------------------------------------------------------------
__global__ __launch_bounds__(256) void ln_k(
    const float* __restrict__ in1, const float* __restrict__ in2,
    const float* __restrict__ g, const float* __restrict__ bta,
    float* __restrict__ outf, ushort* __restrict__ outb)
{
    const int row = blockIdx.x;
    const int t = threadIdx.x;
    float v = in1[(size_t)row * 256 + t];
    if (in2) v += in2[(size_t)row * 256 + t];

    __shared__ float red[4];
    __shared__ float mu_s, rstd_s;
    const int wid = t >> 6, lane = t & 63;

    float s = v;
    #pragma unroll
    for (int o = 32; o; o >>= 1) s += __shfl_xor(s, o);
    if (lane == 0) red[wid] = s;
    __syncthreads();
    if (t == 0) mu_s = (red[0] + red[1] + red[2] + red[3]) * (1.f / 256.f);
    __syncthreads();
    const float mu = mu_s;
    const float dv = v - mu;
    float s2 = dv * dv;
    #pragma unroll
    for (int o = 32; o; o >>= 1) s2 += __shfl_xor(s2, o);
    if (lane == 0) red[wid] = s2;
    __syncthreads();
    if (t == 0) rstd_s = rsqrtf((red[0] + red[1] + red[2] + red[3]) * (1.f / 256.f) + 1e-5f);
    __syncthreads();
    float r = dv * rstd_s * g[t] + bta[t];
    if (outf) outf[(size_t)row * 256 + t] = r;
    if (outb) outb[(size_t)row * 256 + t] = f2b(r);
}

// ---------------------------------------------------------------------------
extern "C" void kernel_launch(void* const* d_in, const int* in_sizes, int n_in,
                              void* d_out, int out_size, void* d_ws, size_t ws_size,
                              hipStream_t stream)
{
    const float* src     = (const float*)d_in[0];
    const float* src2    = (const float*)d_in[1];
    const float* pos     = (const float*)d_in[2];
    const float* mpos    = (const float*)d_in[3];
    const float* value_w = (const float*)d_in[4];
    const float* value_b = (const float*)d_in[5];
    const float* off_w   = (const float*)d_in[6];
    const float* off_b   = (const float*)d_in[7];
    const float* aw_w    = (const float*)d_in[8];
    const float* aw_b    = (const float*)d_in[9];
    const float* out_w   = (const float*)d_in[10];
    const float* out_b   = (const float*)d_in[11];
    const float* ln_g    = (const float*)d_in[12];
    const float* ln_b    = (const float*)d_in[13];
    const float* lin1_w  = (const float*)d_in[14];
    const float* lin1_b  = (const float*)d_in[15];
    const float* lin2_w  = (const float*)d_in[16];
    const float* lin2_b  = (const float*)d_in[17];

    float* outp = (float*)d_out;
    char*  w8   = (char*)d_ws;
    const size_t E = (size_t)NTOK * DMODEL;   // 13,613,056

    // workspace layout (bytes):
    ushort* qb    = (ushort*)(w8);                          // E bf16      (27.2MB)
    ushort* memb  = (ushort*)(w8 + E * 2);                  // E bf16
    ushort* wtb   = (ushort*)(w8 + E * 4);                  // weights bf16 (<2MB)
    ushort* vb    = (ushort*)(w8 + E * 4 + (2u << 20));     // E bf16
    float*  offo  = (float*) (w8 + E * 6 + (2u << 20));     // E f32       (54.5MB)
    float*  awl   = (float*) (w8 + E * 10 + (2u << 20));    // E/2 f32
    ushort* attb  = (ushort*)(w8 + E * 12 + (2u << 20));    // E bf16
    // total: 14E + 2MB = 192.6 MB
    // reuse after earlier stages die:
    float*  bufX  = offo;     // E f32  (off-proj results dead after deform)
    ushort* bufXb = qb;       // E bf16 (q dead after off/aw GEMMs)
    ushort* hidb  = memb;     // FFN hidden chunk (mem dead after value GEMM)
    float*  ffn2f = awl;      // E f32 spans awl+attb regions (both dead by FFN)

    // weight sub-offsets (bf16 elems)
    ushort* value_wt = wtb;             // [256][256]
    ushort* off_wt_t = wtb + 65536;     // [256][256]
    ushort* aw_wt_t  = wtb + 131072;    // [128][256]
    ushort* out_wt_t = wtb + 163840;    // [256][256]
    ushort* lin1_wt  = wtb + 229376;    // [1024][256]
    ushort* lin2_wt  = wtb + 491520;    // [256][1024]

    const dim3 blk(256);
    const int n4 = (int)(E / 4);
    addcvt_k<<<(n4 + 255) / 256, blk, 0, stream>>>(src, pos, qb, n4);
    addcvt_k<<<(n4 + 255) / 256, blk, 0, stream>>>(src2, mpos, memb, n4);
    wtrans_k<<<(65536 + 255) / 256, blk, 0, stream>>>(value_w, value_wt, 256, 256);
    wtrans_k<<<(65536 + 255) / 256, blk, 0, stream>>>(off_w, off_wt_t, 256, 256);
    wtrans_k<<<(32768 + 255) / 256, blk, 0, stream>>>(aw_w, aw_wt_t, 256, 128);
    wtrans_k<<<(65536 + 255) / 256, blk, 0, stream>>>(out_w, out_wt_t, 256, 256);
    wtrans_k<<<(262144 + 255) / 256, blk, 0, stream>>>(lin1_w, lin1_wt, 256, 1024);
    wtrans_k<<<(262144 + 255) / 256, blk, 0, stream>>>(lin2_w, lin2_wt, 1024, 256);

    const int mt = (NTOK + 127) / 128;   // 416
    mgemm_k<<<dim3(mt, 2), blk, 0, stream>>>(memb, value_wt, value_b, nullptr, vb, NTOK, 256, 256, 0);
    mgemm_k<<<dim3(mt, 2), blk, 0, stream>>>(qb, off_wt_t, off_b, offo, nullptr, NTOK, 256, 256, 0);
    mgemm_k<<<dim3(mt, 1), blk, 0, stream>>>(qb, aw_wt_t, aw_b, awl, nullptr, NTOK, 128, 256, 0);

    deform_k<<<dim3(NTOK / 4), blk, 0, stream>>>(vb, offo, awl, attb);

    mgemm_k<<<dim3(mt, 2), blk, 0, stream>>>(attb, out_wt_t, out_b, outp, nullptr, NTOK, 256, 256, 0);
    ln_k<<<dim3(NTOK), blk, 0, stream>>>(outp, src, ln_g, ln_b, bufX, bufXb);

    const int CH = 8192;
    for (int c0 = 0; c0 < NTOK; c0 += CH) {
        int mr = NTOK - c0; if (mr > CH) mr = CH;
        int cmt = (mr + 127) / 128;
        mgemm_k<<<dim3(cmt, 8), blk, 0, stream>>>(bufXb + (size_t)c0 * DMODEL, lin1_wt, lin1_b,
                                                  nullptr, hidb, mr, DFFN, DMODEL, 1);
        mgemm_k<<<dim3(cmt, 2), blk, 0, stream>>>(hidb, lin2_wt, lin2_b,
                                                  ffn2f + (size_t)c0 * DMODEL, nullptr, mr, DMODEL, DFFN, 0);
    }

    ln_k<<<dim3(NTOK), blk, 0, stream>>>(ffn2f, bufX, ln_g, ln_b, outp, nullptr);
}

// Round 3
// 581.900 us; speedup vs baseline: 4.6902x; 1.3545x over previous
//
#include <hip/hip_runtime.h>
#include <math.h>

#define L_TOKN 13294
#define BATCHN 4
#define NTOK (BATCHN * L_TOKN)     // 53176
#define NTOKP 53248                // padded to multiple of 128
#define DMODEL 256
#define DFFN 1024

typedef __attribute__((ext_vector_type(8))) short short8;
typedef __attribute__((ext_vector_type(8))) unsigned short u16x8;
typedef __attribute__((ext_vector_type(4))) float f32x4;

__device__ __forceinline__ ushort f2b(float f) {
    uint u = __float_as_uint(f);
    u += 0x7fff + ((u >> 16) & 1);
    return (ushort)(u >> 16);
}
__device__ __forceinline__ float b2f(uint h) {
    return __uint_as_float(h << 16);
}

__global__ __launch_bounds__(256) void addcvt_k(
    const float* __restrict__ a, const float* __restrict__ b,
    ushort* __restrict__ o, int n4)
{
    int i = blockIdx.x * 256 + threadIdx.x;
    if (i >= n4) return;
    float4 va = ((const float4*)a)[i];
    float4 vb = ((const float4*)b)[i];
    ushort4 r;
    r.x = f2b(va.x + vb.x); r.y = f2b(va.y + vb.y);
    r.z = f2b(va.z + vb.z); r.w = f2b(va.w + vb.w);
    ((ushort4*)o)[i] = r;
}

__global__ __launch_bounds__(256) void wtrans6_k(
    const float* __restrict__ w0, const float* __restrict__ w1,
    const float* __restrict__ w2, const float* __restrict__ w3,
    const float* __restrict__ w4, const float* __restrict__ w5,
    ushort* __restrict__ wtb)
{
    int i = blockIdx.x * 256 + threadIdx.x;
    const float* w; int Kd, Nd; size_t off; int j;
    if      (i < 65536)  { w = w0; Kd = 256;  Nd = 256;  off = 0;      j = i; }
    else if (i < 131072) { w = w1; Kd = 256;  Nd = 256;  off = 65536;  j = i - 65536; }
    else if (i < 163840) { w = w2; Kd = 256;  Nd = 128;  off = 131072; j = i - 131072; }
    else if (i < 229376) { w = w3; Kd = 256;  Nd = 256;  off = 163840; j = i - 163840; }
    else if (i < 491520) { w = w4; Kd = 256;  Nd = 1024; off = 229376; j = i - 229376; }
    else if (i < 753664) { w = w5; Kd = 1024; Nd = 256;  off = 491520; j = i - 491520; }
    else return;
    int k = j / Nd, n = j - k * Nd;
    wtb[off + (size_t)n * Kd + k] = f2b(w[j]);
}

__global__ __launch_bounds__(256) void mgemm_k(
    const ushort* __restrict__ A, const ushort* __restrict__ Wt,
    const float* __restrict__ bias, const float* __restrict__ bias2,
    float* __restrict__ Cf, float* __restrict__ Cf2, ushort* __restrict__ Cb,
    int M, int N, int K, int relu, int nsplit)
{
    __shared__ ushort lds[16384];   // 2 x (A 4096 + B 4096) ushorts = 32KB

    const int t  = threadIdx.x;
    const int m0 = blockIdx.x * 128;
    const int n0 = blockIdx.y * 128;

    const int wv = t >> 6, ln_ = t & 63;
    const int wr = wv >> 1, wc = wv & 1;
    const int fr = ln_ & 15;
    const int kg = ln_ >> 4;

    f32x4 acc[4][4];
    #pragma unroll
    for (int i = 0; i < 4; i++)
        #pragma unroll
        for (int j = 0; j < 4; j++) acc[i][j] = (f32x4)0.0f;

    int aoff[4], boff[4];
    #pragma unroll
    for (int i = 0; i < 4; i++) {
        aoff[i] = (wr * 64 + i * 16 + fr) * 32 + kg * 8;
        boff[i] = 4096 + (wc * 64 + i * 16 + fr) * 32 + kg * 8;
    }

#define STAGE(pbuf, k0) do {                                                       \
    _Pragma("unroll")                                                              \
    for (int ii = 0; ii < 2; ii++) {                                               \
        int c = (wv * 2 + ii) * 64 + ln_;                                          \
        int m = c >> 2, s = c & 3;                                                 \
        const ushort* sa = A  + (size_t)(m0 + m) * K + (k0) + s * 8;               \
        const ushort* sb = Wt + (size_t)(n0 + m) * K + (k0) + s * 8;               \
        __builtin_amdgcn_global_load_lds(                                          \
            (const __attribute__((address_space(1))) unsigned int*)sa,             \
            (__attribute__((address_space(3))) unsigned int*)&lds[(pbuf) * 8192 + (wv * 2 + ii) * 512], \
            16, 0, 0);                                                             \
        __builtin_amdgcn_global_load_lds(                                          \
            (const __attribute__((address_space(1))) unsigned int*)sb,             \
            (__attribute__((address_space(3))) unsigned int*)&lds[(pbuf) * 8192 + 4096 + (wv * 2 + ii) * 512], \
            16, 0, 0);                                                             \
    }                                                                              \
} while (0)

    const int nk = K >> 5;
    STAGE(0, 0);
    __syncthreads();

    for (int ks = 0; ks < nk; ks++) {
        const int p = ks & 1;
        if (ks + 1 < nk) STAGE(p ^ 1, (ks + 1) << 5);

        short8 af[4], bf[4];
        const int pb = p * 8192;
        #pragma unroll
        for (int i = 0; i < 4; i++) {
            af[i] = *(const short8*)&lds[pb + aoff[i]];
            bf[i] = *(const short8*)&lds[pb + boff[i]];
        }
        #pragma unroll
        for (int i = 0; i < 4; i++)
            #pragma unroll
            for (int j = 0; j < 4; j++)
                acc[i][j] = __builtin_amdgcn_mfma_f32_16x16x32_bf16(af[i], bf[j], acc[i][j], 0, 0, 0);

        if (ks + 1 < nk) __syncthreads();
    }
#undef STAGE

    const int N2 = N - nsplit;
    #pragma unroll
    for (int i = 0; i < 4; i++) {
        #pragma unroll
        for (int j = 0; j < 4; j++) {
            int col = n0 + wc * 64 + j * 16 + fr;
            float bv = (col < nsplit) ? bias[col] : bias2[col - nsplit];
            #pragma unroll
            for (int e = 0; e < 4; e++) {
                int row = m0 + wr * 64 + i * 16 + kg * 4 + e;
                if (row >= M) continue;
                float v = acc[i][j][e] + bv;
                if (relu) v = fmaxf(v, 0.f);
                if (col < nsplit) {
                    if (Cf) Cf[(size_t)row * nsplit + col] = v;
                    if (Cb) Cb[(size_t)row * N + col] = f2b(v);
                } else {
                    Cf2[(size_t)row * N2 + (col - nsplit)] = v;
                }
            }
        }
    }
}

__global__ __launch_bounds__(256) void deform_k(
    const ushort* __restrict__ Vb,
    const float* __restrict__ OFF,
    const float* __restrict__ AWL,
    ushort* __restrict__ OUTb)
{
    __shared__ float offs_s[2048];
    __shared__ float aw_s[64 * 17];
    __shared__ int4  pw_s[1024];

    const int t = threadIdx.x;
    const int tok0 = blockIdx.x * 8;

    {
        const float4* so = (const float4*)(OFF + (size_t)tok0 * 256);
        ((float4*)offs_s)[t]       = so[t];
        ((float4*)offs_s)[t + 256] = so[t + 256];
        float4 v = ((const float4*)(AWL + (size_t)tok0 * 128))[t];
        int e = t * 4;
        int tk = e >> 7, r = e & 127, h = r >> 4, p = r & 15;
        float* dst = &aw_s[(tk * 8 + h) * 17 + p];
        dst[0] = v.x; dst[1] = v.y; dst[2] = v.z; dst[3] = v.w;
    }
    __syncthreads();

    if (t < 64) {
        float* a = &aw_s[t * 17];
        float mx = a[0];
        #pragma unroll
        for (int i = 1; i < 16; i++) mx = fmaxf(mx, a[i]);
        float e[16], sm = 0.f;
        #pragma unroll
        for (int i = 0; i < 16; i++) { e[i] = __expf(a[i] - mx); sm += e[i]; }
        float inv = 1.f / sm;
        #pragma unroll
        for (int i = 0; i < 16; i++) a[i] = e[i] * inv;
    }
    __syncthreads();

    const int HWc[4] = {100, 50, 25, 13};
    const int STc[4] = {0, 10000, 12500, 13125};

    #pragma unroll
    for (int it = 0; it < 4; it++) {
        int task = t + it * 256;
        int tk = task >> 7, r = task & 127, h = r >> 4, pp = r & 15, lv = pp >> 2;
        int row = tok0 + tk;
        int b = row / L_TOKN;
        int l = row - b * L_TOKN;
        int st_q, Wq;
        if      (l < 10000) { st_q = 0;     Wq = 100; }
        else if (l < 12500) { st_q = 10000; Wq = 50;  }
        else if (l < 13125) { st_q = 12500; Wq = 25;  }
        else                { st_q = 13125; Wq = 13;  }
        int li = l - st_q;
        int rowi = li / Wq;
        int coli = li - rowi * Wq;
        float rx = (coli + 0.5f) / (float)Wq;
        float ry = (rowi + 0.5f) / (float)Wq;

        int Wl = HWc[lv], stl = STc[lv];
        float Wlf = (float)Wl;
        float ox = offs_s[tk * 256 + h * 32 + lv * 8 + (pp & 3) * 2];
        float oy = offs_s[tk * 256 + h * 32 + lv * 8 + (pp & 3) * 2 + 1];
        float aw = aw_s[(tk * 8 + h) * 17 + pp];

        float x = (rx + ox / Wlf) * Wlf - 0.5f;
        float y = (ry + oy / Wlf) * Wlf - 0.5f;
        float x0f = floorf(x), y0f = floorf(y);
        float wx1 = x - x0f, wy1 = y - y0f;
        float wx0 = 1.f - wx1, wy0 = 1.f - wy1;
        int x0 = (int)x0f, y0 = (int)y0f;
        bool vx0 = (x0 >= 0) & (x0 < Wl);
        bool vx1 = (x0 + 1 >= 0) & (x0 + 1 < Wl);
        bool vy0 = (y0 >= 0) & (y0 < Wl);
        bool vy1 = (y0 + 1 >= 0) & (y0 + 1 < Wl);
        int cx0 = min(max(x0, 0), Wl - 1), cx1 = min(max(x0 + 1, 0), Wl - 1);
        int cy0 = min(max(y0, 0), Wl - 1), cy1 = min(max(y0 + 1, 0), Wl - 1);
        uint i00 = stl + cy0 * Wl + cx0;
        uint i10 = stl + cy0 * Wl + cx1;
        uint i01 = stl + cy1 * Wl + cx0;
        uint i11 = stl + cy1 * Wl + cx1;
        float w00 = wx0 * wy0 * aw * (float)(vx0 & vy0);
        float w10 = wx1 * wy0 * aw * (float)(vx1 & vy0);
        float w01 = wx0 * wy1 * aw * (float)(vx0 & vy1);
        float w11 = wx1 * wy1 * aw * (float)(vx1 & vy1);
        int4 pk;
        pk.x = (int)(i00 | (i10 << 16));
        pk.y = (int)(i01 | (i11 << 16));
        pk.z = (int)((uint)f2b(w00) | ((uint)f2b(w10) << 16));
        pk.w = (int)((uint)f2b(w01) | ((uint)f2b(w11) << 16));
        pw_s[task ^ h] = pk;
    }
    __syncthreads();

    const int tk = t >> 5, h = (t >> 2) & 7, dq = t & 3;
    const int row = tok0 + tk;
    const int b = row / L_TOKN;
    const ushort* Vbase = Vb + (size_t)b * L_TOKN * 256 + h * 32 + dq * 8;
    const int tbase = tk * 128 + h * 16;

    float acc[8];
    #pragma unroll
    for (int e = 0; e < 8; e++) acc[e] = 0.f;

    #pragma unroll
    for (int pp = 0; pp < 16; pp++) {
        int4 pk = pw_s[(tbase + pp) ^ h];
        uint ia = (uint)pk.x, ib = (uint)pk.y;
        float w00 = b2f((uint)pk.z & 0xffffu);
        float w10 = __uint_as_float((uint)pk.z & 0xffff0000u);
        float w01 = b2f((uint)pk.w & 0xffffu);
        float w11 = __uint_as_float((uint)pk.w & 0xffff0000u);
        u16x8 v00 = *(const u16x8*)(Vbase + (size_t)(ia & 0xffffu) * 256);
        u16x8 v10 = *(const u16x8*)(Vbase + (size_t)(ia >> 16) * 256);
        u16x8 v01 = *(const u16x8*)(Vbase + (size_t)(ib & 0xffffu) * 256);
        u16x8 v11 = *(const u16x8*)(Vbase + (size_t)(ib >> 16) * 256);
        #pragma unroll
        for (int e = 0; e < 8; e++) {
            acc[e] += w00 * b2f(v00[e]) + w10 * b2f(v10[e])
                    + w01 * b2f(v01[e]) + w11 * b2f(v11[e]);
        }
    }
    u16x8 o;
    #pragma unroll
    for (int e = 0; e < 8; e++) o[e] = f2b(acc[e]);
    *(u16x8*)(OUTb + (size_t)row * 256 + h * 32 + dq * 8) = o;
}

__global__ __launch_bounds__(256) void ln_k(
    const float* __restrict__ in1, const float* __restrict__ in2,
    const float* __restrict__ g, const float* __restrict__ bta,
    float* __restrict__ outf, ushort* __restrict__ outb)
{
    const int r = blockIdx.x * 4 + (threadIdx.x >> 6);
    const int lane = threadIdx.x & 63;
    float4 v = *((const float4*)(in1 + (size_t)r * 256) + lane);
    if (in2) {
        float4 v2 = *((const float4*)(in2 + (size_t)r * 256) + lane);
        v.x += v2.x; v.y += v2.y; v.z += v2.z; v.w += v2.w;
    }
    float s = v.x + v.y + v.z + v.w;
    #pragma unroll
    for (int o = 32; o; o >>= 1) s += __shfl_xor(s, o);
    float mu = s * (1.f / 256.f);
    float4 d; d.x = v.x - mu; d.y = v.y - mu; d.z = v.z - mu; d.w = v.w - mu;
    float s2 = d.x * d.x + d.y * d.y + d.z * d.z + d.w * d.w;
    #pragma unroll
    for (int o = 32; o; o >>= 1) s2 += __shfl_xor(s2, o);
    float rstd = rsqrtf(s2 * (1.f / 256.f) + 1e-5f);
    float4 gg = ((const float4*)g)[lane];
    float4 bb = ((const float4*)bta)[lane];
    float4 out;
    out.x = d.x * rstd * gg.x + bb.x;
    out.y = d.y * rstd * gg.y + bb.y;
    out.z = d.z * rstd * gg.z + bb.z;
    out.w = d.w * rstd * gg.w + bb.w;
    if (outf) *((float4*)(outf + (size_t)r * 256) + lane) = out;
    if (outb) {
        ushort4 ob;
        ob.x = f2b(out.x); ob.y = f2b(out.y); ob.z = f2b(out.z); ob.w = f2b(out.w);
        *((ushort4*)(outb + (size_t)r * 256) + lane) = ob;
    }
}

extern "C" void kernel_launch(void* const* d_in, const int* in_sizes, int n_in,
                              void* d_out, int out_size, void* d_ws, size_t ws_size,
                              hipStream_t stream)
{
    const float* src     = (const float*)d_in[0];
    const float* src2    = (const float*)d_in[1];
    const float* pos     = (const float*)d_in[2];
    const float* mpos    = (const float*)d_in[3];
    const float* value_w = (const float*)d_in[4];
    const float* value_b = (const float*)d_in[5];
    const float* off_w   = (const float*)d_in[6];
    const float* off_b   = (const float*)d_in[7];
    const float* aw_w    = (const float*)d_in[8];
    const float* aw_b    = (const float*)d_in[9];
    const float* out_w   = (const float*)d_in[10];
    const float* out_b   = (const float*)d_in[11];
    const float* ln_g    = (const float*)d_in[12];
    const float* ln_b    = (const float*)d_in[13];
    const float* lin1_w  = (const float*)d_in[14];
    const float* lin1_b  = (const float*)d_in[15];
    const float* lin2_w  = (const float*)d_in[16];
    const float* lin2_b  = (const float*)d_in[17];

    float* outp = (float*)d_out;
    char*  w8   = (char*)d_ws;

    const size_t SLAB = (size_t)NTOKP * 256 * 2;         // 27,262,976
    ushort* wtb  = (ushort*)(w8);
    ushort* qb   = (ushort*)(w8 + 1572864);
    ushort* memb = (ushort*)(w8 + 1572864 + SLAB);
    ushort* vb   = (ushort*)(w8 + 1572864 + SLAB * 2);
    float*  offo = (float*) (w8 + 1572864 + SLAB * 3);
    float*  awl  = (float*) (w8 + 1572864 + SLAB * 5);
    ushort* attb = (ushort*)(w8 + 1572864 + SLAB * 6);

    ushort* bufXb = qb;
    float*  bufX  = offo;
    float*  ffn2f = (float*)memb;
    ushort* hidb  = attb;

    ushort* value_wt = wtb;
    ushort* offaw_wt = wtb + 65536;
    ushort* out_wt   = wtb + 163840;
    ushort* lin1_wt  = wtb + 229376;
    ushort* lin2_wt  = wtb + 491520;

    const dim3 blk(256);
    const int n4 = NTOK * DMODEL / 4;
    addcvt_k<<<(n4 + 255) / 256, blk, 0, stream>>>(src, pos, qb, n4);
    addcvt_k<<<(n4 + 255) / 256, blk, 0, stream>>>(src2, mpos, memb, n4);
    wtrans6_k<<<(753664 + 255) / 256, blk, 0, stream>>>(value_w, off_w, aw_w, out_w,
                                                        lin1_w, lin2_w, wtb);

    const int mt = NTOKP / 128;   // 416
    mgemm_k<<<dim3(mt, 2), blk, 0, stream>>>(memb, value_wt, value_b, nullptr,
                                             nullptr, nullptr, vb, NTOK, 256, 256, 0, 256);
    mgemm_k<<<dim3(mt, 3), blk, 0, stream>>>(qb, offaw_wt, off_b, aw_b,
                                             offo, awl, nullptr, NTOK, 384, 256, 0, 256);

    deform_k<<<dim3(NTOK / 8), blk, 0, stream>>>(vb, offo, awl, attb);

    mgemm_k<<<dim3(mt, 2), blk, 0, stream>>>(attb, out_wt, out_b, nullptr,
                                             outp, nullptr, nullptr, NTOK, 256, 256, 0, 256);
    ln_k<<<dim3(NTOK / 4), blk, 0, stream>>>(outp, src, ln_g, ln_b, bufX, bufXb);

    const int CH = 13312;
    for (int c0 = 0; c0 < NTOK; c0 += CH) {
        int mr = NTOK - c0; if (mr > CH) mr = CH;
        mgemm_k<<<dim3(104, 8), blk, 0, stream>>>(bufXb + (size_t)c0 * DMODEL, lin1_wt,
                                                  lin1_b, nullptr, nullptr, nullptr, hidb,
                                                  mr, DFFN, DMODEL, 1, DFFN);
        mgemm_k<<<dim3(104, 2), blk, 0, stream>>>(hidb, lin2_wt, lin2_b, nullptr,
                                                  ffn2f + (size_t)c0 * DMODEL, nullptr, nullptr,
                                                  mr, DMODEL, DFFN, 0, DMODEL);
    }

    ln_k<<<dim3(NTOK / 4), blk, 0, stream>>>(ffn2f, bufX, ln_g, ln_b, outp, nullptr);
}

// Round 5
// 475.974 us; speedup vs baseline: 5.7340x; 1.2225x over previous
//
#include <hip/hip_runtime.h>
#include <math.h>

#define L_TOKN 13294
#define BATCHN 4
#define NTOK (BATCHN * L_TOKN)     // 53176
#define NTOKP 53248                // padded to multiple of 128
#define DMODEL 256
#define DFFN 1024

typedef __attribute__((ext_vector_type(8))) short short8;
typedef __attribute__((ext_vector_type(8))) unsigned short u16x8;
typedef __attribute__((ext_vector_type(4))) float f32x4;

__device__ __forceinline__ ushort f2b(float f) {
    uint u = __float_as_uint(f);
    u += 0x7fff + ((u >> 16) & 1);
    return (ushort)(u >> 16);
}
__device__ __forceinline__ float b2f(uint h) {
    return __uint_as_float(h << 16);
}

// ---------------------------------------------------------------------------
// merged addcvt: qb = bf16(src+pos), memb = bf16(src2+mpos)
// ---------------------------------------------------------------------------
__global__ __launch_bounds__(256) void addcvt2_k(
    const float* __restrict__ s1, const float* __restrict__ p1,
    const float* __restrict__ s2, const float* __restrict__ p2,
    ushort* __restrict__ o1, ushort* __restrict__ o2, int n4)
{
    int i = blockIdx.x * 256 + threadIdx.x;
    const float* a; const float* b; ushort* o; int j;
    if (i < n4) { a = s1; b = p1; o = o1; j = i; }
    else        { a = s2; b = p2; o = o2; j = i - n4; if (j >= n4) return; }
    float4 va = ((const float4*)a)[j];
    float4 vb = ((const float4*)b)[j];
    ushort4 r;
    r.x = f2b(va.x + vb.x); r.y = f2b(va.y + vb.y);
    r.z = f2b(va.z + vb.z); r.w = f2b(va.w + vb.w);
    ((ushort4*)o)[j] = r;
}

// ---------------------------------------------------------------------------
// all-weights transpose+convert: W[K][N] f32 -> Wt[N][K] bf16 (6 segments)
// ---------------------------------------------------------------------------
__global__ __launch_bounds__(256) void wtrans6_k(
    const float* __restrict__ w0, const float* __restrict__ w1,
    const float* __restrict__ w2, const float* __restrict__ w3,
    const float* __restrict__ w4, const float* __restrict__ w5,
    ushort* __restrict__ wtb)
{
    int i = blockIdx.x * 256 + threadIdx.x;
    const float* w; int Nd; size_t off; int j;
    if      (i < 65536)  { w = w0; Nd = 256;  off = 0;      j = i; }
    else if (i < 131072) { w = w1; Nd = 256;  off = 65536;  j = i - 65536; }
    else if (i < 163840) { w = w2; Nd = 128;  off = 131072; j = i - 131072; }
    else if (i < 229376) { w = w3; Nd = 256;  off = 163840; j = i - 163840; }
    else if (i < 491520) { w = w4; Nd = 1024; off = 229376; j = i - 229376; }
    else if (i < 753664) { w = w5; Nd = 256;  off = 491520; j = i - 491520; }
    else return;
    int Kd = (i < 491520) ? 256 : 1024;
    int k = j / Nd, n = j - k * Nd;
    wtb[off + (size_t)n * Kd + k] = f2b(w[j]);
}

// ---------------------------------------------------------------------------
// bf16 MFMA GEMM, 128x128 tile, BK=32, global_load_lds double-buffered.
// A rows must be padded to tile multiple (no A predication). Wt[N][K].
// bias split at nsplit (bias2 for col>=nsplit). Outputs: f32 Cf / bf16 Cb.
// NOTE: must NOT be run in-place (A aliasing C races across blocks).
// ---------------------------------------------------------------------------
__global__ __launch_bounds__(256) void mgemm_k(
    const ushort* __restrict__ A, const ushort* __restrict__ Wt,
    const float* __restrict__ bias, const float* __restrict__ bias2,
    float* __restrict__ Cf, ushort* __restrict__ Cb,
    int M, int N, int K, int relu, int nsplit)
{
    __shared__ ushort lds[16384];   // 2 x (A 4096 + B 4096) ushorts = 32KB

    const int t  = threadIdx.x;
    const int m0 = blockIdx.x * 128;
    const int n0 = blockIdx.y * 128;

    const int wv = t >> 6, ln_ = t & 63;
    const int wr = wv >> 1, wc = wv & 1;
    const int fr = ln_ & 15;
    const int kg = ln_ >> 4;

    f32x4 acc[4][4];
    #pragma unroll
    for (int i = 0; i < 4; i++)
        #pragma unroll
        for (int j = 0; j < 4; j++) acc[i][j] = (f32x4)0.0f;

    int aoff[4], boff[4];
    #pragma unroll
    for (int i = 0; i < 4; i++) {
        aoff[i] = (wr * 64 + i * 16 + fr) * 32 + kg * 8;
        boff[i] = 4096 + (wc * 64 + i * 16 + fr) * 32 + kg * 8;
    }

#define STAGE(pbuf, k0) do {                                                       \
    _Pragma("unroll")                                                              \
    for (int ii = 0; ii < 2; ii++) {                                               \
        int c = (wv * 2 + ii) * 64 + ln_;                                          \
        int m = c >> 2, s = c & 3;                                                 \
        const ushort* sa = A  + (size_t)(m0 + m) * K + (k0) + s * 8;               \
        const ushort* sb = Wt + (size_t)(n0 + m) * K + (k0) + s * 8;               \
        __builtin_amdgcn_global_load_lds(                                          \
            (const __attribute__((address_space(1))) unsigned int*)sa,             \
            (__attribute__((address_space(3))) unsigned int*)&lds[(pbuf) * 8192 + (wv * 2 + ii) * 512], \
            16, 0, 0);                                                             \
        __builtin_amdgcn_global_load_lds(                                          \
            (const __attribute__((address_space(1))) unsigned int*)sb,             \
            (__attribute__((address_space(3))) unsigned int*)&lds[(pbuf) * 8192 + 4096 + (wv * 2 + ii) * 512], \
            16, 0, 0);                                                             \
    }                                                                              \
} while (0)

    const int nk = K >> 5;
    STAGE(0, 0);
    __syncthreads();

    for (int ks = 0; ks < nk; ks++) {
        const int p = ks & 1;
        if (ks + 1 < nk) STAGE(p ^ 1, (ks + 1) << 5);

        short8 af[4], bf[4];
        const int pb = p * 8192;
        #pragma unroll
        for (int i = 0; i < 4; i++) {
            af[i] = *(const short8*)&lds[pb + aoff[i]];
            bf[i] = *(const short8*)&lds[pb + boff[i]];
        }
        #pragma unroll
        for (int i = 0; i < 4; i++)
            #pragma unroll
            for (int j = 0; j < 4; j++)
                acc[i][j] = __builtin_amdgcn_mfma_f32_16x16x32_bf16(af[i], bf[j], acc[i][j], 0, 0, 0);

        if (ks + 1 < nk) __syncthreads();
    }
#undef STAGE

    #pragma unroll
    for (int i = 0; i < 4; i++) {
        #pragma unroll
        for (int j = 0; j < 4; j++) {
            int col = n0 + wc * 64 + j * 16 + fr;
            float bv = (col < nsplit) ? bias[col] : bias2[col - nsplit];
            #pragma unroll
            for (int e = 0; e < 4; e++) {
                int row = m0 + wr * 64 + i * 16 + kg * 4 + e;
                if (row >= M) continue;
                float v = acc[i][j][e] + bv;
                if (relu) v = fmaxf(v, 0.f);
                if (Cf) Cf[(size_t)row * N + col] = v;
                if (Cb) Cb[(size_t)row * N + col] = f2b(v);
            }
        }
    }
}

// ---------------------------------------------------------------------------
// Deformable attention core. 8 tokens/block, 256 threads, 2 phases.
// Phase B: 1024 point-tasks; offsets/logits read DIRECTLY from global (bf16),
// softmax over 16 lanes via shfl_xor; pack (idx x4 u16, w x4 bf16) -> LDS.
// Phase C: 32 thr/token (8 heads x 4), 8 channels/thread, 16B gather loads.
// OFFAW layout per row (384 bf16): [0..255] offsets, [256..383] aw logits.
// ---------------------------------------------------------------------------
__global__ __launch_bounds__(256) void deform_k(
    const ushort* __restrict__ Vb,      // bf16 (NTOK,256)
    const ushort* __restrict__ OFFAW,   // bf16 (NTOK,384)
    ushort* __restrict__ OUTb)          // bf16 (NTOK,256)
{
    __shared__ int4 pw_s[1024];

    const int t = threadIdx.x;
    const int tok0 = blockIdx.x * 8;

    const int HWc[4] = {100, 50, 25, 13};
    const int STc[4] = {0, 10000, 12500, 13125};

    // phase B: 4 iterations x (16 groups x 16 pp-lanes)
    const int g  = t >> 4;     // group-slot within iteration
    const int pp = t & 15;     // point id within (tok,head)
    const int lv = pp >> 2;

    #pragma unroll
    for (int it = 0; it < 4; it++) {
        int grp = it * 16 + g;           // 0..63 = tk*8 + h
        int tk = grp >> 3, h = grp & 7;
        int row = tok0 + tk;
        int b = row / L_TOKN;
        int l = row - b * L_TOKN;
        int st_q, Wq;
        if      (l < 10000) { st_q = 0;     Wq = 100; }
        else if (l < 12500) { st_q = 10000; Wq = 50;  }
        else if (l < 13125) { st_q = 12500; Wq = 25;  }
        else                { st_q = 13125; Wq = 13;  }
        int li = l - st_q;
        int rowi = li / Wq;
        int coli = li - rowi * Wq;
        float rx = (coli + 0.5f) / (float)Wq;
        float ry = (rowi + 0.5f) / (float)Wq;

        const size_t rbase = (size_t)row * 384;
        uint oxy = *(const uint*)(OFFAW + rbase + h * 32 + pp * 2);
        float ox = b2f(oxy & 0xffffu);
        float oy = b2f(oxy >> 16);
        float lg = b2f((uint)OFFAW[rbase + 256 + h * 16 + pp]);
        float mx = lg;
        #pragma unroll
        for (int o = 8; o; o >>= 1) mx = fmaxf(mx, __shfl_xor(mx, o));
        float ex = __expf(lg - mx);
        float sm = ex;
        #pragma unroll
        for (int o = 8; o; o >>= 1) sm += __shfl_xor(sm, o);
        float aw = ex / sm;

        int Wl = HWc[lv], stl = STc[lv];
        float Wlf = (float)Wl;
        float x = (rx + ox / Wlf) * Wlf - 0.5f;
        float y = (ry + oy / Wlf) * Wlf - 0.5f;
        float x0f = floorf(x), y0f = floorf(y);
        float wx1 = x - x0f, wy1 = y - y0f;
        float wx0 = 1.f - wx1, wy0 = 1.f - wy1;
        int x0 = (int)x0f, y0 = (int)y0f;
        bool vx0 = (x0 >= 0) & (x0 < Wl);
        bool vx1 = (x0 + 1 >= 0) & (x0 + 1 < Wl);
        bool vy0 = (y0 >= 0) & (y0 < Wl);
        bool vy1 = (y0 + 1 >= 0) & (y0 + 1 < Wl);
        int cx0 = min(max(x0, 0), Wl - 1), cx1 = min(max(x0 + 1, 0), Wl - 1);
        int cy0 = min(max(y0, 0), Wl - 1), cy1 = min(max(y0 + 1, 0), Wl - 1);
        uint i00 = stl + cy0 * Wl + cx0;
        uint i10 = stl + cy0 * Wl + cx1;
        uint i01 = stl + cy1 * Wl + cx0;
        uint i11 = stl + cy1 * Wl + cx1;
        float w00 = wx0 * wy0 * aw * (float)(vx0 & vy0);
        float w10 = wx1 * wy0 * aw * (float)(vx1 & vy0);
        float w01 = wx0 * wy1 * aw * (float)(vx0 & vy1);
        float w11 = wx1 * wy1 * aw * (float)(vx1 & vy1);
        int4 pk;
        pk.x = (int)(i00 | (i10 << 16));
        pk.y = (int)(i01 | (i11 << 16));
        pk.z = (int)((uint)f2b(w00) | ((uint)f2b(w10) << 16));
        pk.w = (int)((uint)f2b(w01) | ((uint)f2b(w11) << 16));
        int task = grp * 16 + pp;
        pw_s[task ^ h] = pk;
    }
    __syncthreads();

    // phase C: gather. thread = tk(3) | h(3) | dq(2); 8 channels/thread
    const int tk = t >> 5, h = (t >> 2) & 7, dq = t & 3;
    const int row = tok0 + tk;
    const int b = row / L_TOKN;
    const ushort* Vbase = Vb + (size_t)b * L_TOKN * 256 + h * 32 + dq * 8;
    const int tbase = tk * 128 + h * 16;

    float acc[8];
    #pragma unroll
    for (int e = 0; e < 8; e++) acc[e] = 0.f;

    #pragma unroll
    for (int pq = 0; pq < 16; pq++) {
        int4 pk = pw_s[(tbase + pq) ^ h];
        uint ia = (uint)pk.x, ib = (uint)pk.y;
        float w00 = b2f((uint)pk.z & 0xffffu);
        float w10 = __uint_as_float((uint)pk.z & 0xffff0000u);
        float w01 = b2f((uint)pk.w & 0xffffu);
        float w11 = __uint_as_float((uint)pk.w & 0xffff0000u);
        u16x8 v00 = *(const u16x8*)(Vbase + (size_t)(ia & 0xffffu) * 256);
        u16x8 v10 = *(const u16x8*)(Vbase + (size_t)(ia >> 16) * 256);
        u16x8 v01 = *(const u16x8*)(Vbase + (size_t)(ib & 0xffffu) * 256);
        u16x8 v11 = *(const u16x8*)(Vbase + (size_t)(ib >> 16) * 256);
        #pragma unroll
        for (int e = 0; e < 8; e++) {
            acc[e] += w00 * b2f(v00[e]) + w10 * b2f(v10[e])
                    + w01 * b2f(v01[e]) + w11 * b2f(v11[e]);
        }
    }
    u16x8 o;
    #pragma unroll
    for (int e = 0; e < 8; e++) o[e] = f2b(acc[e]);
    *(u16x8*)(OUTb + (size_t)row * 256 + h * 32 + dq * 8) = o;
}

// ---------------------------------------------------------------------------
// LayerNorm(256), one wave per row. Inputs: (af f32 | ab bf16) + optional
// (bf2 f32 | bb2 bf16) residual. Outputs: of f32 and/or ob bf16.
// ---------------------------------------------------------------------------
__global__ __launch_bounds__(256) void ln_k(
    const float* __restrict__ af, const ushort* __restrict__ ab,
    const float* __restrict__ bf2, const ushort* __restrict__ bb2,
    const float* __restrict__ g, const float* __restrict__ bta,
    float* __restrict__ of, ushort* __restrict__ ob)
{
    const int r = blockIdx.x * 4 + (threadIdx.x >> 6);
    const int lane = threadIdx.x & 63;
    float4 v;
    if (af) {
        v = *((const float4*)(af + (size_t)r * 256) + lane);
    } else {
        ushort4 u = *((const ushort4*)(ab + (size_t)r * 256) + lane);
        v.x = b2f(u.x); v.y = b2f(u.y); v.z = b2f(u.z); v.w = b2f(u.w);
    }
    if (bf2) {
        float4 v2 = *((const float4*)(bf2 + (size_t)r * 256) + lane);
        v.x += v2.x; v.y += v2.y; v.z += v2.z; v.w += v2.w;
    } else if (bb2) {
        ushort4 u = *((const ushort4*)(bb2 + (size_t)r * 256) + lane);
        v.x += b2f(u.x); v.y += b2f(u.y); v.z += b2f(u.z); v.w += b2f(u.w);
    }
    float s = v.x + v.y + v.z + v.w;
    #pragma unroll
    for (int o = 32; o; o >>= 1) s += __shfl_xor(s, o);
    float mu = s * (1.f / 256.f);
    float4 d; d.x = v.x - mu; d.y = v.y - mu; d.z = v.z - mu; d.w = v.w - mu;
    float s2 = d.x * d.x + d.y * d.y + d.z * d.z + d.w * d.w;
    #pragma unroll
    for (int o = 32; o; o >>= 1) s2 += __shfl_xor(s2, o);
    float rstd = rsqrtf(s2 * (1.f / 256.f) + 1e-5f);
    float4 gg = ((const float4*)g)[lane];
    float4 bb = ((const float4*)bta)[lane];
    float4 out;
    out.x = d.x * rstd * gg.x + bb.x;
    out.y = d.y * rstd * gg.y + bb.y;
    out.z = d.z * rstd * gg.z + bb.z;
    out.w = d.w * rstd * gg.w + bb.w;
    if (of) *((float4*)(of + (size_t)r * 256) + lane) = out;
    if (ob) {
        ushort4 o4;
        o4.x = f2b(out.x); o4.y = f2b(out.y); o4.z = f2b(out.z); o4.w = f2b(out.w);
        *((ushort4*)(ob + (size_t)r * 256) + lane) = o4;
    }
}

// ---------------------------------------------------------------------------
extern "C" void kernel_launch(void* const* d_in, const int* in_sizes, int n_in,
                              void* d_out, int out_size, void* d_ws, size_t ws_size,
                              hipStream_t stream)
{
    const float* src     = (const float*)d_in[0];
    const float* src2    = (const float*)d_in[1];
    const float* pos     = (const float*)d_in[2];
    const float* mpos    = (const float*)d_in[3];
    const float* value_w = (const float*)d_in[4];
    const float* value_b = (const float*)d_in[5];
    const float* off_w   = (const float*)d_in[6];
    const float* off_b   = (const float*)d_in[7];
    const float* aw_w    = (const float*)d_in[8];
    const float* aw_b    = (const float*)d_in[9];
    const float* out_w   = (const float*)d_in[10];
    const float* out_b   = (const float*)d_in[11];
    const float* ln_g    = (const float*)d_in[12];
    const float* ln_b    = (const float*)d_in[13];
    const float* lin1_w  = (const float*)d_in[14];
    const float* lin1_b  = (const float*)d_in[15];
    const float* lin2_w  = (const float*)d_in[16];
    const float* lin2_b  = (const float*)d_in[17];

    float* outp = (float*)d_out;
    char*  w8   = (char*)d_ws;

    const size_t SLAB = (size_t)NTOKP * 256 * 2;            // 27,262,976
    const size_t OASZ = (size_t)NTOKP * 384 * 2;            // 40,894,464
    ushort* wtb    = (ushort*)(w8);                          // 1.5MB
    ushort* offawb = (ushort*)(w8 + 1572864);                // bf16 (NTOKP,384)
    ushort* qb     = (ushort*)(w8 + 1572864 + OASZ);
    ushort* memb   = (ushort*)(w8 + 1572864 + OASZ + SLAB);
    ushort* vb     = (ushort*)(w8 + 1572864 + OASZ + SLAB * 2);
    ushort* attb   = (ushort*)(w8 + 1572864 + OASZ + SLAB * 3);

    // aliases after death:
    ushort* hidb   = offawb;   // FFN hidden chunk (spans offawb+qb, both dead)
    ushort* bufXb  = memb;     // LN1 out bf16 (memb dead after value GEMM)
    ushort* projb  = vb;       // out-proj result (vb dead after deform) - NOT in-place!

    ushort* value_wt = wtb;            // [256][256]
    ushort* offaw_wt = wtb + 65536;    // [384][256]
    ushort* out_wt   = wtb + 163840;   // [256][256]
    ushort* lin1_wt  = wtb + 229376;   // [1024][256]
    ushort* lin2_wt  = wtb + 491520;   // [256][1024]

    const dim3 blk(256);
    const int n4 = NTOK * DMODEL / 4;
    addcvt2_k<<<(2 * n4 + 255) / 256, blk, 0, stream>>>(src, pos, src2, mpos, qb, memb, n4);
    wtrans6_k<<<(753664 + 255) / 256, blk, 0, stream>>>(value_w, off_w, aw_w, out_w,
                                                        lin1_w, lin2_w, wtb);

    const int mt = NTOKP / 128;   // 416
    mgemm_k<<<dim3(mt, 2), blk, 0, stream>>>(memb, value_wt, value_b, nullptr,
                                             nullptr, vb, NTOK, 256, 256, 0, 256);
    mgemm_k<<<dim3(mt, 3), blk, 0, stream>>>(qb, offaw_wt, off_b, aw_b,
                                             nullptr, offawb, NTOK, 384, 256, 0, 256);

    deform_k<<<dim3(NTOK / 8), blk, 0, stream>>>(vb, offawb, attb);

    // out proj: attb -> projb (separate buffer; in-place would race)
    mgemm_k<<<dim3(mt, 2), blk, 0, stream>>>(attb, out_wt, out_b, nullptr,
                                             nullptr, projb, NTOK, 256, 256, 0, 256);
    // x = LN(attn_proj + src) -> bufXb bf16
    ln_k<<<dim3(NTOK / 4), blk, 0, stream>>>(nullptr, projb, src, nullptr,
                                             ln_g, ln_b, nullptr, bufXb);

    // FFN in 2 chunks of 26624 rows; hidden in hidb; FFN2 f32 -> outp (d_out)
    const int CH = 26624;
    for (int c0 = 0; c0 < NTOK; c0 += CH) {
        int mr = NTOK - c0; if (mr > CH) mr = CH;
        int cmt = (mr + 127) / 128;
        mgemm_k<<<dim3(cmt, 8), blk, 0, stream>>>(bufXb + (size_t)c0 * DMODEL, lin1_wt,
                                                  lin1_b, nullptr, nullptr, hidb,
                                                  mr, DFFN, DMODEL, 1, DFFN);
        mgemm_k<<<dim3(cmt, 2), blk, 0, stream>>>(hidb, lin2_wt, lin2_b, nullptr,
                                                  outp + (size_t)c0 * DMODEL, nullptr,
                                                  mr, DMODEL, DFFN, 0, DMODEL);
    }

    // out = LN(ffn + x), in-place on d_out
    ln_k<<<dim3(NTOK / 4), blk, 0, stream>>>(outp, nullptr, nullptr, bufXb,
                                             ln_g, ln_b, outp, nullptr);
}

// Round 6
// 444.321 us; speedup vs baseline: 6.1425x; 1.0712x over previous
//
#include <hip/hip_runtime.h>
#include <math.h>

#define L_TOKN 13294
#define BATCHN 4
#define NTOK (BATCHN * L_TOKN)     // 53176
#define NTOKP 53248                // padded to multiple of 128
#define DMODEL 256
#define DFFN 1024

typedef __attribute__((ext_vector_type(8))) short short8;
typedef __attribute__((ext_vector_type(8))) unsigned short u16x8;
typedef __attribute__((ext_vector_type(4))) float f32x4;
typedef __attribute__((ext_vector_type(2))) float f32x2;

__device__ __forceinline__ ushort f2b(float f) {
    uint u = __float_as_uint(f);
    u += 0x7fff + ((u >> 16) & 1);
    return (ushort)(u >> 16);
}
__device__ __forceinline__ float b2f(uint h) {
    return __uint_as_float(h << 16);
}

// ---------------------------------------------------------------------------
// merged addcvt: qb = bf16(src+pos), memb = bf16(src2+mpos)
// ---------------------------------------------------------------------------
__global__ __launch_bounds__(256) void addcvt2_k(
    const float* __restrict__ s1, const float* __restrict__ p1,
    const float* __restrict__ s2, const float* __restrict__ p2,
    ushort* __restrict__ o1, ushort* __restrict__ o2, int n4)
{
    int i = blockIdx.x * 256 + threadIdx.x;
    const float* a; const float* b; ushort* o; int j;
    if (i < n4) { a = s1; b = p1; o = o1; j = i; }
    else        { a = s2; b = p2; o = o2; j = i - n4; if (j >= n4) return; }
    float4 va = ((const float4*)a)[j];
    float4 vb = ((const float4*)b)[j];
    ushort4 r;
    r.x = f2b(va.x + vb.x); r.y = f2b(va.y + vb.y);
    r.z = f2b(va.z + vb.z); r.w = f2b(va.w + vb.w);
    ((ushort4*)o)[j] = r;
}

// ---------------------------------------------------------------------------
// all-weights transpose+convert: W[K][N] f32 -> Wt[N][K] bf16 (6 segments)
// ---------------------------------------------------------------------------
__global__ __launch_bounds__(256) void wtrans6_k(
    const float* __restrict__ w0, const float* __restrict__ w1,
    const float* __restrict__ w2, const float* __restrict__ w3,
    const float* __restrict__ w4, const float* __restrict__ w5,
    ushort* __restrict__ wtb)
{
    int i = blockIdx.x * 256 + threadIdx.x;
    const float* w; int Nd; size_t off; int j;
    if      (i < 65536)  { w = w0; Nd = 256;  off = 0;      j = i; }
    else if (i < 131072) { w = w1; Nd = 256;  off = 65536;  j = i - 65536; }
    else if (i < 163840) { w = w2; Nd = 128;  off = 131072; j = i - 131072; }
    else if (i < 229376) { w = w3; Nd = 256;  off = 163840; j = i - 163840; }
    else if (i < 491520) { w = w4; Nd = 1024; off = 229376; j = i - 229376; }
    else if (i < 753664) { w = w5; Nd = 256;  off = 491520; j = i - 491520; }
    else return;
    int Kd = (i < 491520) ? 256 : 1024;
    int k = j / Nd, n = j - k * Nd;
    wtb[off + (size_t)n * Kd + k] = f2b(w[j]);
}

// ---------------------------------------------------------------------------
// bf16 MFMA GEMM, 128x128 tile, BK=32, global_load_lds double-buffered.
// A rows must be padded to tile multiple. Wt[N][K]. NOT safe in-place.
// ---------------------------------------------------------------------------
__global__ __launch_bounds__(256) void mgemm_k(
    const ushort* __restrict__ A, const ushort* __restrict__ Wt,
    const float* __restrict__ bias, const float* __restrict__ bias2,
    float* __restrict__ Cf, ushort* __restrict__ Cb,
    int M, int N, int K, int relu, int nsplit)
{
    __shared__ ushort lds[16384];

    const int t  = threadIdx.x;
    const int m0 = blockIdx.x * 128;
    const int n0 = blockIdx.y * 128;

    const int wv = t >> 6, ln_ = t & 63;
    const int wr = wv >> 1, wc = wv & 1;
    const int fr = ln_ & 15;
    const int kg = ln_ >> 4;

    f32x4 acc[4][4];
    #pragma unroll
    for (int i = 0; i < 4; i++)
        #pragma unroll
        for (int j = 0; j < 4; j++) acc[i][j] = (f32x4)0.0f;

    int aoff[4], boff[4];
    #pragma unroll
    for (int i = 0; i < 4; i++) {
        aoff[i] = (wr * 64 + i * 16 + fr) * 32 + kg * 8;
        boff[i] = 4096 + (wc * 64 + i * 16 + fr) * 32 + kg * 8;
    }

#define STAGE(pbuf, k0) do {                                                       \
    _Pragma("unroll")                                                              \
    for (int ii = 0; ii < 2; ii++) {                                               \
        int c = (wv * 2 + ii) * 64 + ln_;                                          \
        int m = c >> 2, s = c & 3;                                                 \
        const ushort* sa = A  + (size_t)(m0 + m) * K + (k0) + s * 8;               \
        const ushort* sb = Wt + (size_t)(n0 + m) * K + (k0) + s * 8;               \
        __builtin_amdgcn_global_load_lds(                                          \
            (const __attribute__((address_space(1))) unsigned int*)sa,             \
            (__attribute__((address_space(3))) unsigned int*)&lds[(pbuf) * 8192 + (wv * 2 + ii) * 512], \
            16, 0, 0);                                                             \
        __builtin_amdgcn_global_load_lds(                                          \
            (const __attribute__((address_space(1))) unsigned int*)sb,             \
            (__attribute__((address_space(3))) unsigned int*)&lds[(pbuf) * 8192 + 4096 + (wv * 2 + ii) * 512], \
            16, 0, 0);                                                             \
    }                                                                              \
} while (0)

    const int nk = K >> 5;
    STAGE(0, 0);
    __syncthreads();

    for (int ks = 0; ks < nk; ks++) {
        const int p = ks & 1;
        if (ks + 1 < nk) STAGE(p ^ 1, (ks + 1) << 5);

        short8 af[4], bf[4];
        const int pb = p * 8192;
        #pragma unroll
        for (int i = 0; i < 4; i++) {
            af[i] = *(const short8*)&lds[pb + aoff[i]];
            bf[i] = *(const short8*)&lds[pb + boff[i]];
        }
        #pragma unroll
        for (int i = 0; i < 4; i++)
            #pragma unroll
            for (int j = 0; j < 4; j++)
                acc[i][j] = __builtin_amdgcn_mfma_f32_16x16x32_bf16(af[i], bf[j], acc[i][j], 0, 0, 0);

        if (ks + 1 < nk) __syncthreads();
    }
#undef STAGE

    #pragma unroll
    for (int i = 0; i < 4; i++) {
        #pragma unroll
        for (int j = 0; j < 4; j++) {
            int col = n0 + wc * 64 + j * 16 + fr;
            float bv = (col < nsplit) ? bias[col] : bias2[col - nsplit];
            #pragma unroll
            for (int e = 0; e < 4; e++) {
                int row = m0 + wr * 64 + i * 16 + kg * 4 + e;
                if (row >= M) continue;
                float v = acc[i][j][e] + bv;
                if (relu) v = fmaxf(v, 0.f);
                if (Cf) Cf[(size_t)row * N + col] = v;
                if (Cb) Cb[(size_t)row * N + col] = f2b(v);
            }
        }
    }
}

// ---------------------------------------------------------------------------
// Deformable attention v3: barrier-free, wave-independent. 256 thr = 4 waves,
// each wave owns 2 tokens. Phase B: 256 tasks/wave compute softmax weights +
// PRE-SCALED byte offsets (batch folded) -> padded LDS. Phase C: 32 thr/token
// gather with 32-bit voffsets off a uniform base; f32x2 packed channel math.
// ---------------------------------------------------------------------------
__global__ __launch_bounds__(256) void deform_k(
    const ushort* __restrict__ Vb,      // bf16 (NTOK,256)
    const ushort* __restrict__ OFFAW,   // bf16 (NTOK,384): [0:256) offs, [256:384) logits
    ushort* __restrict__ OUTb)          // bf16 (NTOK,256)
{
    __shared__ uint4 pw_idx[4][2][136];   // [wave][tok][h*17+pp] scaled offsets
    __shared__ uint2 pw_w[4][2][136];     // packed bf16 weights x4

    const int t = threadIdx.x;
    const int wv = t >> 6, lane = t & 63;
    const int tok0 = blockIdx.x * 8 + wv * 2;

    const int HWc[4] = {100, 50, 25, 13};
    const int STc[4] = {0, 10000, 12500, 13125};

    // ---- phase B: 2 tok x 8 h x 16 pp = 256 tasks over 64 lanes, 4 iters
    const int ppb = lane & 15;
    const int lvb = ppb >> 2;
    #pragma unroll
    for (int it = 0; it < 4; it++) {
        int tk = it >> 1;
        int h  = ((it & 1) << 2) + (lane >> 4);
        int row = tok0 + tk;
        int b = row / L_TOKN;
        int l = row - b * L_TOKN;
        int st_q, Wq;
        if      (l < 10000) { st_q = 0;     Wq = 100; }
        else if (l < 12500) { st_q = 10000; Wq = 50;  }
        else if (l < 13125) { st_q = 12500; Wq = 25;  }
        else                { st_q = 13125; Wq = 13;  }
        int li = l - st_q;
        int rowi = li / Wq;
        int coli = li - rowi * Wq;
        float rx = (coli + 0.5f) / (float)Wq;
        float ry = (rowi + 0.5f) / (float)Wq;

        const size_t rbase = (size_t)row * 384;
        uint oxy = *(const uint*)(OFFAW + rbase + h * 32 + ppb * 2);
        float ox = b2f(oxy & 0xffffu);
        float oy = b2f(oxy >> 16);
        float lg = b2f((uint)OFFAW[rbase + 256 + h * 16 + ppb]);
        float mx = lg;
        #pragma unroll
        for (int o = 8; o; o >>= 1) mx = fmaxf(mx, __shfl_xor(mx, o));
        float ex = __expf(lg - mx);
        float sm = ex;
        #pragma unroll
        for (int o = 8; o; o >>= 1) sm += __shfl_xor(sm, o);
        float aw = ex / sm;

        int Wl = HWc[lvb], stl = STc[lvb];
        float Wlf = (float)Wl;
        float x = (rx + ox / Wlf) * Wlf - 0.5f;
        float y = (ry + oy / Wlf) * Wlf - 0.5f;
        float x0f = floorf(x), y0f = floorf(y);
        float wx1 = x - x0f, wy1 = y - y0f;
        float wx0 = 1.f - wx1, wy0 = 1.f - wy1;
        int x0 = (int)x0f, y0 = (int)y0f;
        bool vx0 = (x0 >= 0) & (x0 < Wl);
        bool vx1 = (x0 + 1 >= 0) & (x0 + 1 < Wl);
        bool vy0 = (y0 >= 0) & (y0 < Wl);
        bool vy1 = (y0 + 1 >= 0) & (y0 + 1 < Wl);
        int cx0 = min(max(x0, 0), Wl - 1), cx1 = min(max(x0 + 1, 0), Wl - 1);
        int cy0 = min(max(y0, 0), Wl - 1), cy1 = min(max(y0 + 1, 0), Wl - 1);
        // scaled byte offsets with batch folded in (token_row * 512 bytes)
        uint gb = (uint)(b * L_TOKN + stl);
        uint4 o4;
        o4.x = (gb + cy0 * Wl + cx0) * 512u;
        o4.y = (gb + cy0 * Wl + cx1) * 512u;
        o4.z = (gb + cy1 * Wl + cx0) * 512u;
        o4.w = (gb + cy1 * Wl + cx1) * 512u;
        float w00 = wx0 * wy0 * aw * (float)(vx0 & vy0);
        float w10 = wx1 * wy0 * aw * (float)(vx1 & vy0);
        float w01 = wx0 * wy1 * aw * (float)(vx0 & vy1);
        float w11 = wx1 * wy1 * aw * (float)(vx1 & vy1);
        uint2 wp;
        wp.x = (uint)f2b(w00) | ((uint)f2b(w10) << 16);
        wp.y = (uint)f2b(w01) | ((uint)f2b(w11) << 16);
        pw_idx[wv][tk][h * 17 + ppb] = o4;
        pw_w[wv][tk][h * 17 + ppb]   = wp;
    }

    // wave-internal LDS handoff: drain ds ops, pin ordering
    asm volatile("s_waitcnt lgkmcnt(0)" ::: "memory");
    __builtin_amdgcn_sched_barrier(0);

    // ---- phase C: gather. lane = tk(1) | h(3) | dq(2); 8 channels/thread
    const int tk = lane >> 5;
    const int h  = (lane >> 2) & 7;
    const int dq = lane & 3;
    const int row = tok0 + tk;
    const uint choff = (uint)(h * 64 + dq * 16);   // byte offset within token row
    const char* __restrict__ vbase = (const char*)Vb;

    f32x2 acc2[4];
    #pragma unroll
    for (int k = 0; k < 4; k++) acc2[k] = (f32x2)0.0f;

    #pragma unroll 8
    for (int pq = 0; pq < 16; pq++) {
        uint4 o4 = pw_idx[wv][tk][h * 17 + pq];
        uint2 wp = pw_w[wv][tk][h * 17 + pq];
        float w00 = b2f(wp.x & 0xffffu);
        float w10 = __uint_as_float(wp.x & 0xffff0000u);
        float w01 = b2f(wp.y & 0xffffu);
        float w11 = __uint_as_float(wp.y & 0xffff0000u);
        uint4 v00 = *(const uint4*)(vbase + o4.x + choff);
        uint4 v10 = *(const uint4*)(vbase + o4.y + choff);
        uint4 v01 = *(const uint4*)(vbase + o4.z + choff);
        uint4 v11 = *(const uint4*)(vbase + o4.w + choff);
        const uint* p00 = (const uint*)&v00;
        const uint* p10 = (const uint*)&v10;
        const uint* p01 = (const uint*)&v01;
        const uint* p11 = (const uint*)&v11;
        #pragma unroll
        for (int k = 0; k < 4; k++) {
            f32x2 a0, a1, a2, a3;
            a0.x = __uint_as_float(p00[k] << 16); a0.y = __uint_as_float(p00[k] & 0xffff0000u);
            a1.x = __uint_as_float(p10[k] << 16); a1.y = __uint_as_float(p10[k] & 0xffff0000u);
            a2.x = __uint_as_float(p01[k] << 16); a2.y = __uint_as_float(p01[k] & 0xffff0000u);
            a3.x = __uint_as_float(p11[k] << 16); a3.y = __uint_as_float(p11[k] & 0xffff0000u);
            acc2[k] += a0 * w00 + a1 * w10 + a2 * w01 + a3 * w11;
        }
    }
    ushort4 olo, ohi;
    olo.x = f2b(acc2[0].x); olo.y = f2b(acc2[0].y);
    olo.z = f2b(acc2[1].x); olo.w = f2b(acc2[1].y);
    ohi.x = f2b(acc2[2].x); ohi.y = f2b(acc2[2].y);
    ohi.z = f2b(acc2[3].x); ohi.w = f2b(acc2[3].y);
    ushort* op = OUTb + (size_t)row * 256 + h * 32 + dq * 8;
    *(ushort4*)op = olo;
    *(ushort4*)(op + 4) = ohi;
}

// ---------------------------------------------------------------------------
// LayerNorm(256), one wave per row. Inputs: (af f32 | ab bf16) + optional
// (bf2 f32 | bb2 bf16) residual. Outputs: of f32 and/or ob bf16.
// ---------------------------------------------------------------------------
__global__ __launch_bounds__(256) void ln_k(
    const float* __restrict__ af, const ushort* __restrict__ ab,
    const float* __restrict__ bf2, const ushort* __restrict__ bb2,
    const float* __restrict__ g, const float* __restrict__ bta,
    float* __restrict__ of, ushort* __restrict__ ob)
{
    const int r = blockIdx.x * 4 + (threadIdx.x >> 6);
    const int lane = threadIdx.x & 63;
    float4 v;
    if (af) {
        v = *((const float4*)(af + (size_t)r * 256) + lane);
    } else {
        ushort4 u = *((const ushort4*)(ab + (size_t)r * 256) + lane);
        v.x = b2f(u.x); v.y = b2f(u.y); v.z = b2f(u.z); v.w = b2f(u.w);
    }
    if (bf2) {
        float4 v2 = *((const float4*)(bf2 + (size_t)r * 256) + lane);
        v.x += v2.x; v.y += v2.y; v.z += v2.z; v.w += v2.w;
    } else if (bb2) {
        ushort4 u = *((const ushort4*)(bb2 + (size_t)r * 256) + lane);
        v.x += b2f(u.x); v.y += b2f(u.y); v.z += b2f(u.z); v.w += b2f(u.w);
    }
    float s = v.x + v.y + v.z + v.w;
    #pragma unroll
    for (int o = 32; o; o >>= 1) s += __shfl_xor(s, o);
    float mu = s * (1.f / 256.f);
    float4 d; d.x = v.x - mu; d.y = v.y - mu; d.z = v.z - mu; d.w = v.w - mu;
    float s2 = d.x * d.x + d.y * d.y + d.z * d.z + d.w * d.w;
    #pragma unroll
    for (int o = 32; o; o >>= 1) s2 += __shfl_xor(s2, o);
    float rstd = rsqrtf(s2 * (1.f / 256.f) + 1e-5f);
    float4 gg = ((const float4*)g)[lane];
    float4 bb = ((const float4*)bta)[lane];
    float4 out;
    out.x = d.x * rstd * gg.x + bb.x;
    out.y = d.y * rstd * gg.y + bb.y;
    out.z = d.z * rstd * gg.z + bb.z;
    out.w = d.w * rstd * gg.w + bb.w;
    if (of) *((float4*)(of + (size_t)r * 256) + lane) = out;
    if (ob) {
        ushort4 o4;
        o4.x = f2b(out.x); o4.y = f2b(out.y); o4.z = f2b(out.z); o4.w = f2b(out.w);
        *((ushort4*)(ob + (size_t)r * 256) + lane) = o4;
    }
}

// ---------------------------------------------------------------------------
extern "C" void kernel_launch(void* const* d_in, const int* in_sizes, int n_in,
                              void* d_out, int out_size, void* d_ws, size_t ws_size,
                              hipStream_t stream)
{
    const float* src     = (const float*)d_in[0];
    const float* src2    = (const float*)d_in[1];
    const float* pos     = (const float*)d_in[2];
    const float* mpos    = (const float*)d_in[3];
    const float* value_w = (const float*)d_in[4];
    const float* value_b = (const float*)d_in[5];
    const float* off_w   = (const float*)d_in[6];
    const float* off_b   = (const float*)d_in[7];
    const float* aw_w    = (const float*)d_in[8];
    const float* aw_b    = (const float*)d_in[9];
    const float* out_w   = (const float*)d_in[10];
    const float* out_b   = (const float*)d_in[11];
    const float* ln_g    = (const float*)d_in[12];
    const float* ln_b    = (const float*)d_in[13];
    const float* lin1_w  = (const float*)d_in[14];
    const float* lin1_b  = (const float*)d_in[15];
    const float* lin2_w  = (const float*)d_in[16];
    const float* lin2_b  = (const float*)d_in[17];

    float* outp = (float*)d_out;
    char*  w8   = (char*)d_ws;

    const size_t SLAB = (size_t)NTOKP * 256 * 2;            // 27,262,976
    const size_t OASZ = (size_t)NTOKP * 384 * 2;            // 40,894,464
    ushort* wtb    = (ushort*)(w8);                          // 1.5MB
    ushort* offawb = (ushort*)(w8 + 1572864);                // bf16 (NTOKP,384)
    ushort* qb     = (ushort*)(w8 + 1572864 + OASZ);
    ushort* memb   = (ushort*)(w8 + 1572864 + OASZ + SLAB);
    ushort* vb     = (ushort*)(w8 + 1572864 + OASZ + SLAB * 2);
    ushort* attb   = (ushort*)(w8 + 1572864 + OASZ + SLAB * 3);

    // aliases after death:
    ushort* hidb   = offawb;   // FFN hidden chunk (spans offawb+qb, both dead)
    ushort* bufXb  = memb;     // LN1 out bf16 (memb dead after value GEMM)
    ushort* projb  = vb;       // out-proj result (vb dead after deform)
    ushort* ffn2b  = attb;     // FFN2 bf16 out (attb dead after out-proj)

    ushort* value_wt = wtb;            // [256][256]
    ushort* offaw_wt = wtb + 65536;    // [384][256]
    ushort* out_wt   = wtb + 163840;   // [256][256]
    ushort* lin1_wt  = wtb + 229376;   // [1024][256]
    ushort* lin2_wt  = wtb + 491520;   // [256][1024]

    const dim3 blk(256);
    const int n4 = NTOK * DMODEL / 4;
    addcvt2_k<<<(2 * n4 + 255) / 256, blk, 0, stream>>>(src, pos, src2, mpos, qb, memb, n4);
    wtrans6_k<<<(753664 + 255) / 256, blk, 0, stream>>>(value_w, off_w, aw_w, out_w,
                                                        lin1_w, lin2_w, wtb);

    const int mt = NTOKP / 128;   // 416
    mgemm_k<<<dim3(mt, 2), blk, 0, stream>>>(memb, value_wt, value_b, nullptr,
                                             nullptr, vb, NTOK, 256, 256, 0, 256);
    mgemm_k<<<dim3(mt, 3), blk, 0, stream>>>(qb, offaw_wt, off_b, aw_b,
                                             nullptr, offawb, NTOK, 384, 256, 0, 256);

    deform_k<<<dim3(NTOK / 8), blk, 0, stream>>>(vb, offawb, attb);

    // out proj: attb -> projb (separate buffer; in-place would race)
    mgemm_k<<<dim3(mt, 2), blk, 0, stream>>>(attb, out_wt, out_b, nullptr,
                                             nullptr, projb, NTOK, 256, 256, 0, 256);
    // x = LN(attn_proj + src) -> bufXb bf16
    ln_k<<<dim3(NTOK / 4), blk, 0, stream>>>(nullptr, projb, src, nullptr,
                                             ln_g, ln_b, nullptr, bufXb);

    // FFN in 2 chunks; hidden in hidb; FFN2 -> ffn2b (bf16)
    const int CH = 26624;
    for (int c0 = 0; c0 < NTOK; c0 += CH) {
        int mr = NTOK - c0; if (mr > CH) mr = CH;
        int cmt = (mr + 127) / 128;
        mgemm_k<<<dim3(cmt, 8), blk, 0, stream>>>(bufXb + (size_t)c0 * DMODEL, lin1_wt,
                                                  lin1_b, nullptr, nullptr, hidb,
                                                  mr, DFFN, DMODEL, 1, DFFN);
        mgemm_k<<<dim3(cmt, 2), blk, 0, stream>>>(hidb, lin2_wt, lin2_b, nullptr,
                                                  nullptr, ffn2b + (size_t)c0 * DMODEL,
                                                  mr, DMODEL, DFFN, 0, DMODEL);
    }

    // out = LN(ffn + x) -> d_out f32
    ln_k<<<dim3(NTOK / 4), blk, 0, stream>>>(nullptr, ffn2b, nullptr, bufXb,
                                             ln_g, ln_b, outp, nullptr);
}

// Round 7
// 421.752 us; speedup vs baseline: 6.4712x; 1.0535x over previous
//
#include <hip/hip_runtime.h>
#include <math.h>

#define L_TOKN 13294
#define BATCHN 4
#define NTOK (BATCHN * L_TOKN)     // 53176
#define NTOKP 53248                // padded to multiple of 128
#define DMODEL 256
#define DFFN 1024

typedef __attribute__((ext_vector_type(8))) short short8;
typedef __attribute__((ext_vector_type(4))) float f32x4;
typedef __attribute__((ext_vector_type(2))) float f32x2;

__device__ __forceinline__ ushort f2b(float f) {
    uint u = __float_as_uint(f);
    u += 0x7fff + ((u >> 16) & 1);
    return (ushort)(u >> 16);
}
__device__ __forceinline__ float b2f(uint h) {
    return __uint_as_float(h << 16);
}

// ---------------------------------------------------------------------------
// prep: [0, 2*n4)  addcvt (qb = bf16(src+pos), memb = bf16(src2+mpos))
//       [2*n4, +753664) weight transpose/convert W[K][N] f32 -> Wt[N][K] bf16
// ---------------------------------------------------------------------------
__global__ __launch_bounds__(256) void prep_k(
    const float* __restrict__ s1, const float* __restrict__ p1,
    const float* __restrict__ s2, const float* __restrict__ p2,
    ushort* __restrict__ o1, ushort* __restrict__ o2,
    const float* __restrict__ w0, const float* __restrict__ w1,
    const float* __restrict__ w2, const float* __restrict__ w3,
    const float* __restrict__ w4, const float* __restrict__ w5,
    ushort* __restrict__ wtb, int n4)
{
    int i = blockIdx.x * 256 + threadIdx.x;
    if (i < 2 * n4) {
        const float* a; const float* b; ushort* o; int j;
        if (i < n4) { a = s1; b = p1; o = o1; j = i; }
        else        { a = s2; b = p2; o = o2; j = i - n4; }
        float4 va = ((const float4*)a)[j];
        float4 vb = ((const float4*)b)[j];
        ushort4 r;
        r.x = f2b(va.x + vb.x); r.y = f2b(va.y + vb.y);
        r.z = f2b(va.z + vb.z); r.w = f2b(va.w + vb.w);
        ((ushort4*)o)[j] = r;
        return;
    }
    int i2 = i - 2 * n4;
    const float* w; int Nd; size_t off; int j;
    if      (i2 < 65536)  { w = w0; Nd = 256;  off = 0;      j = i2; }
    else if (i2 < 131072) { w = w1; Nd = 256;  off = 65536;  j = i2 - 65536; }
    else if (i2 < 163840) { w = w2; Nd = 128;  off = 131072; j = i2 - 131072; }
    else if (i2 < 229376) { w = w3; Nd = 256;  off = 163840; j = i2 - 163840; }
    else if (i2 < 491520) { w = w4; Nd = 1024; off = 229376; j = i2 - 229376; }
    else if (i2 < 753664) { w = w5; Nd = 256;  off = 491520; j = i2 - 491520; }
    else return;
    int Kd = (i2 < 491520) ? 256 : 1024;
    int k = j / Nd, n = j - k * Nd;
    wtb[off + (size_t)n * Kd + k] = f2b(w[j]);
}

// ---------------------------------------------------------------------------
// bf16 MFMA GEMM core, 128x128 tile, BK=32, global_load_lds double-buffered.
// A rows must be padded to tile multiple. Wt[N][K]. NOT safe in-place.
// ---------------------------------------------------------------------------
__device__ __forceinline__ void gemm_core(
    const ushort* __restrict__ A, const ushort* __restrict__ Wt,
    const float* __restrict__ bias, const float* __restrict__ bias2,
    float* __restrict__ Cf, ushort* __restrict__ Cb,
    int M, int N, int K, int relu, int nsplit, int m0, int n0)
{
    __shared__ ushort lds[16384];

    const int t  = threadIdx.x;
    const int wv = t >> 6, ln_ = t & 63;
    const int wr = wv >> 1, wc = wv & 1;
    const int fr = ln_ & 15;
    const int kg = ln_ >> 4;

    f32x4 acc[4][4];
    #pragma unroll
    for (int i = 0; i < 4; i++)
        #pragma unroll
        for (int j = 0; j < 4; j++) acc[i][j] = (f32x4)0.0f;

    int aoff[4], boff[4];
    #pragma unroll
    for (int i = 0; i < 4; i++) {
        aoff[i] = (wr * 64 + i * 16 + fr) * 32 + kg * 8;
        boff[i] = 4096 + (wc * 64 + i * 16 + fr) * 32 + kg * 8;
    }

#define STAGE(pbuf, k0) do {                                                       \
    _Pragma("unroll")                                                              \
    for (int ii = 0; ii < 2; ii++) {                                               \
        int c = (wv * 2 + ii) * 64 + ln_;                                          \
        int m = c >> 2, s = c & 3;                                                 \
        const ushort* sa = A  + (size_t)(m0 + m) * K + (k0) + s * 8;               \
        const ushort* sb = Wt + (size_t)(n0 + m) * K + (k0) + s * 8;               \
        __builtin_amdgcn_global_load_lds(                                          \
            (const __attribute__((address_space(1))) unsigned int*)sa,             \
            (__attribute__((address_space(3))) unsigned int*)&lds[(pbuf) * 8192 + (wv * 2 + ii) * 512], \
            16, 0, 0);                                                             \
        __builtin_amdgcn_global_load_lds(                                          \
            (const __attribute__((address_space(1))) unsigned int*)sb,             \
            (__attribute__((address_space(3))) unsigned int*)&lds[(pbuf) * 8192 + 4096 + (wv * 2 + ii) * 512], \
            16, 0, 0);                                                             \
    }                                                                              \
} while (0)

    const int nk = K >> 5;
    STAGE(0, 0);
    __syncthreads();

    for (int ks = 0; ks < nk; ks++) {
        const int p = ks & 1;
        if (ks + 1 < nk) STAGE(p ^ 1, (ks + 1) << 5);

        short8 af[4], bf[4];
        const int pb = p * 8192;
        #pragma unroll
        for (int i = 0; i < 4; i++) {
            af[i] = *(const short8*)&lds[pb + aoff[i]];
            bf[i] = *(const short8*)&lds[pb + boff[i]];
        }
        #pragma unroll
        for (int i = 0; i < 4; i++)
            #pragma unroll
            for (int j = 0; j < 4; j++)
                acc[i][j] = __builtin_amdgcn_mfma_f32_16x16x32_bf16(af[i], bf[j], acc[i][j], 0, 0, 0);

        if (ks + 1 < nk) __syncthreads();
    }
#undef STAGE

    #pragma unroll
    for (int i = 0; i < 4; i++) {
        #pragma unroll
        for (int j = 0; j < 4; j++) {
            int col = n0 + wc * 64 + j * 16 + fr;
            float bv = (col < nsplit) ? bias[col] : bias2[col - nsplit];
            #pragma unroll
            for (int e = 0; e < 4; e++) {
                int row = m0 + wr * 64 + i * 16 + kg * 4 + e;
                if (row >= M) continue;
                float v = acc[i][j][e] + bv;
                if (relu) v = fmaxf(v, 0.f);
                if (Cf) Cf[(size_t)row * N + col] = v;
                if (Cb) Cb[(size_t)row * N + col] = f2b(v);
            }
        }
    }
}

// generic GEMM: n-tile on blockIdx.x (L2 A-reuse), m-strip on blockIdx.y
__global__ __launch_bounds__(256) void mgemm_k(
    const ushort* __restrict__ A, const ushort* __restrict__ Wt,
    const float* __restrict__ bias, const float* __restrict__ bias2,
    float* __restrict__ Cf, ushort* __restrict__ Cb,
    int M, int N, int K, int relu, int nsplit)
{
    gemm_core(A, Wt, bias, bias2, Cf, Cb, M, N, K, relu, nsplit,
              blockIdx.y * 128, blockIdx.x * 128);
}

// merged value-proj (x<2) + offaw-proj (x>=2), both K=256
__global__ __launch_bounds__(256) void projs_k(
    const ushort* __restrict__ memb, const ushort* __restrict__ qb,
    const ushort* __restrict__ value_wt, const ushort* __restrict__ offaw_wt,
    const float* __restrict__ value_b, const float* __restrict__ off_b,
    const float* __restrict__ aw_b,
    ushort* __restrict__ vb, ushort* __restrict__ offawb)
{
    const int x = blockIdx.x;
    const int m0 = blockIdx.y * 128;
    const ushort* A; const ushort* Wt; const float* b1; const float* b2;
    ushort* Cb; int N, n0;
    if (x < 2) { A = memb; Wt = value_wt; b1 = value_b; b2 = value_b;
                 Cb = vb; N = 256; n0 = x * 128; }
    else       { A = qb;   Wt = offaw_wt; b1 = off_b;   b2 = aw_b;
                 Cb = offawb; N = 384; n0 = (x - 2) * 128; }
    gemm_core(A, Wt, b1, b2, nullptr, Cb, NTOK, N, 256, 0, 256, m0, n0);
}

// ---------------------------------------------------------------------------
// Deformable attention v3 (unchanged from round 6): barrier-free, 4 waves x
// 2 tokens. Phase B: softmax + pre-scaled byte offsets -> LDS. Phase C:
// 32 thr/token gather, f32x2 packed channel math.
// ---------------------------------------------------------------------------
__global__ __launch_bounds__(256) void deform_k(
    const ushort* __restrict__ Vb,      // bf16 (NTOK,256)
    const ushort* __restrict__ OFFAW,   // bf16 (NTOK,384)
    ushort* __restrict__ OUTb)          // bf16 (NTOK,256)
{
    __shared__ uint4 pw_idx[4][2][136];
    __shared__ uint2 pw_w[4][2][136];

    const int t = threadIdx.x;
    const int wv = t >> 6, lane = t & 63;
    const int tok0 = blockIdx.x * 8 + wv * 2;

    const int HWc[4] = {100, 50, 25, 13};
    const int STc[4] = {0, 10000, 12500, 13125};

    const int ppb = lane & 15;
    const int lvb = ppb >> 2;
    #pragma unroll
    for (int it = 0; it < 4; it++) {
        int tk = it >> 1;
        int h  = ((it & 1) << 2) + (lane >> 4);
        int row = tok0 + tk;
        int b = row / L_TOKN;
        int l = row - b * L_TOKN;
        int st_q, Wq;
        if      (l < 10000) { st_q = 0;     Wq = 100; }
        else if (l < 12500) { st_q = 10000; Wq = 50;  }
        else if (l < 13125) { st_q = 12500; Wq = 25;  }
        else                { st_q = 13125; Wq = 13;  }
        int li = l - st_q;
        int rowi = li / Wq;
        int coli = li - rowi * Wq;
        float rx = (coli + 0.5f) / (float)Wq;
        float ry = (rowi + 0.5f) / (float)Wq;

        const size_t rbase = (size_t)row * 384;
        uint oxy = *(const uint*)(OFFAW + rbase + h * 32 + ppb * 2);
        float ox = b2f(oxy & 0xffffu);
        float oy = b2f(oxy >> 16);
        float lg = b2f((uint)OFFAW[rbase + 256 + h * 16 + ppb]);
        float mx = lg;
        #pragma unroll
        for (int o = 8; o; o >>= 1) mx = fmaxf(mx, __shfl_xor(mx, o));
        float ex = __expf(lg - mx);
        float sm = ex;
        #pragma unroll
        for (int o = 8; o; o >>= 1) sm += __shfl_xor(sm, o);
        float aw = ex / sm;

        int Wl = HWc[lvb], stl = STc[lvb];
        float Wlf = (float)Wl;
        float x = (rx + ox / Wlf) * Wlf - 0.5f;
        float y = (ry + oy / Wlf) * Wlf - 0.5f;
        float x0f = floorf(x), y0f = floorf(y);
        float wx1 = x - x0f, wy1 = y - y0f;
        float wx0 = 1.f - wx1, wy0 = 1.f - wy1;
        int x0 = (int)x0f, y0 = (int)y0f;
        bool vx0 = (x0 >= 0) & (x0 < Wl);
        bool vx1 = (x0 + 1 >= 0) & (x0 + 1 < Wl);
        bool vy0 = (y0 >= 0) & (y0 < Wl);
        bool vy1 = (y0 + 1 >= 0) & (y0 + 1 < Wl);
        int cx0 = min(max(x0, 0), Wl - 1), cx1 = min(max(x0 + 1, 0), Wl - 1);
        int cy0 = min(max(y0, 0), Wl - 1), cy1 = min(max(y0 + 1, 0), Wl - 1);
        uint gb = (uint)(b * L_TOKN + stl);
        uint4 o4;
        o4.x = (gb + cy0 * Wl + cx0) * 512u;
        o4.y = (gb + cy0 * Wl + cx1) * 512u;
        o4.z = (gb + cy1 * Wl + cx0) * 512u;
        o4.w = (gb + cy1 * Wl + cx1) * 512u;
        float w00 = wx0 * wy0 * aw * (float)(vx0 & vy0);
        float w10 = wx1 * wy0 * aw * (float)(vx1 & vy0);
        float w01 = wx0 * wy1 * aw * (float)(vx0 & vy1);
        float w11 = wx1 * wy1 * aw * (float)(vx1 & vy1);
        uint2 wp;
        wp.x = (uint)f2b(w00) | ((uint)f2b(w10) << 16);
        wp.y = (uint)f2b(w01) | ((uint)f2b(w11) << 16);
        pw_idx[wv][tk][h * 17 + ppb] = o4;
        pw_w[wv][tk][h * 17 + ppb]   = wp;
    }

    asm volatile("s_waitcnt lgkmcnt(0)" ::: "memory");
    __builtin_amdgcn_sched_barrier(0);

    const int tk = lane >> 5;
    const int h  = (lane >> 2) & 7;
    const int dq = lane & 3;
    const int row = tok0 + tk;
    const uint choff = (uint)(h * 64 + dq * 16);
    const char* __restrict__ vbase = (const char*)Vb;

    f32x2 acc2[4];
    #pragma unroll
    for (int k = 0; k < 4; k++) acc2[k] = (f32x2)0.0f;

    #pragma unroll 8
    for (int pq = 0; pq < 16; pq++) {
        uint4 o4 = pw_idx[wv][tk][h * 17 + pq];
        uint2 wp = pw_w[wv][tk][h * 17 + pq];
        float w00 = b2f(wp.x & 0xffffu);
        float w10 = __uint_as_float(wp.x & 0xffff0000u);
        float w01 = b2f(wp.y & 0xffffu);
        float w11 = __uint_as_float(wp.y & 0xffff0000u);
        uint4 v00 = *(const uint4*)(vbase + o4.x + choff);
        uint4 v10 = *(const uint4*)(vbase + o4.y + choff);
        uint4 v01 = *(const uint4*)(vbase + o4.z + choff);
        uint4 v11 = *(const uint4*)(vbase + o4.w + choff);
        const uint* p00 = (const uint*)&v00;
        const uint* p10 = (const uint*)&v10;
        const uint* p01 = (const uint*)&v01;
        const uint* p11 = (const uint*)&v11;
        #pragma unroll
        for (int k = 0; k < 4; k++) {
            f32x2 a0, a1, a2, a3;
            a0.x = __uint_as_float(p00[k] << 16); a0.y = __uint_as_float(p00[k] & 0xffff0000u);
            a1.x = __uint_as_float(p10[k] << 16); a1.y = __uint_as_float(p10[k] & 0xffff0000u);
            a2.x = __uint_as_float(p01[k] << 16); a2.y = __uint_as_float(p01[k] & 0xffff0000u);
            a3.x = __uint_as_float(p11[k] << 16); a3.y = __uint_as_float(p11[k] & 0xffff0000u);
            acc2[k] += a0 * w00 + a1 * w10 + a2 * w01 + a3 * w11;
        }
    }
    ushort4 olo, ohi;
    olo.x = f2b(acc2[0].x); olo.y = f2b(acc2[0].y);
    olo.z = f2b(acc2[1].x); olo.w = f2b(acc2[1].y);
    ohi.x = f2b(acc2[2].x); ohi.y = f2b(acc2[2].y);
    ohi.z = f2b(acc2[3].x); ohi.w = f2b(acc2[3].y);
    ushort* op = OUTb + (size_t)row * 256 + h * 32 + dq * 8;
    *(ushort4*)op = olo;
    *(ushort4*)(op + 4) = ohi;
}

// ---------------------------------------------------------------------------
// LayerNorm(256), one wave per row. Inputs: (af f32 | ab bf16) + optional
// (bf2 f32 | bb2 bf16) residual. Outputs: of f32 and/or ob bf16.
// ---------------------------------------------------------------------------
__global__ __launch_bounds__(256) void ln_k(
    const float* __restrict__ af, const ushort* __restrict__ ab,
    const float* __restrict__ bf2, const ushort* __restrict__ bb2,
    const float* __restrict__ g, const float* __restrict__ bta,
    float* __restrict__ of, ushort* __restrict__ ob)
{
    const int r = blockIdx.x * 4 + (threadIdx.x >> 6);
    const int lane = threadIdx.x & 63;
    float4 v;
    if (af) {
        v = *((const float4*)(af + (size_t)r * 256) + lane);
    } else {
        ushort4 u = *((const ushort4*)(ab + (size_t)r * 256) + lane);
        v.x = b2f(u.x); v.y = b2f(u.y); v.z = b2f(u.z); v.w = b2f(u.w);
    }
    if (bf2) {
        float4 v2 = *((const float4*)(bf2 + (size_t)r * 256) + lane);
        v.x += v2.x; v.y += v2.y; v.z += v2.z; v.w += v2.w;
    } else if (bb2) {
        ushort4 u = *((const ushort4*)(bb2 + (size_t)r * 256) + lane);
        v.x += b2f(u.x); v.y += b2f(u.y); v.z += b2f(u.z); v.w += b2f(u.w);
    }
    float s = v.x + v.y + v.z + v.w;
    #pragma unroll
    for (int o = 32; o; o >>= 1) s += __shfl_xor(s, o);
    float mu = s * (1.f / 256.f);
    float4 d; d.x = v.x - mu; d.y = v.y - mu; d.z = v.z - mu; d.w = v.w - mu;
    float s2 = d.x * d.x + d.y * d.y + d.z * d.z + d.w * d.w;
    #pragma unroll
    for (int o = 32; o; o >>= 1) s2 += __shfl_xor(s2, o);
    float rstd = rsqrtf(s2 * (1.f / 256.f) + 1e-5f);
    float4 gg = ((const float4*)g)[lane];
    float4 bb = ((const float4*)bta)[lane];
    float4 out;
    out.x = d.x * rstd * gg.x + bb.x;
    out.y = d.y * rstd * gg.y + bb.y;
    out.z = d.z * rstd * gg.z + bb.z;
    out.w = d.w * rstd * gg.w + bb.w;
    if (of) *((float4*)(of + (size_t)r * 256) + lane) = out;
    if (ob) {
        ushort4 o4;
        o4.x = f2b(out.x); o4.y = f2b(out.y); o4.z = f2b(out.z); o4.w = f2b(out.w);
        *((ushort4*)(ob + (size_t)r * 256) + lane) = o4;
    }
}

// ---------------------------------------------------------------------------
extern "C" void kernel_launch(void* const* d_in, const int* in_sizes, int n_in,
                              void* d_out, int out_size, void* d_ws, size_t ws_size,
                              hipStream_t stream)
{
    const float* src     = (const float*)d_in[0];
    const float* src2    = (const float*)d_in[1];
    const float* pos     = (const float*)d_in[2];
    const float* mpos    = (const float*)d_in[3];
    const float* value_w = (const float*)d_in[4];
    const float* value_b = (const float*)d_in[5];
    const float* off_w   = (const float*)d_in[6];
    const float* off_b   = (const float*)d_in[7];
    const float* aw_w    = (const float*)d_in[8];
    const float* aw_b    = (const float*)d_in[9];
    const float* out_w   = (const float*)d_in[10];
    const float* out_b   = (const float*)d_in[11];
    const float* ln_g    = (const float*)d_in[12];
    const float* ln_b    = (const float*)d_in[13];
    const float* lin1_w  = (const float*)d_in[14];
    const float* lin1_b  = (const float*)d_in[15];
    const float* lin2_w  = (const float*)d_in[16];
    const float* lin2_b  = (const float*)d_in[17];

    float* outp = (float*)d_out;
    char*  w8   = (char*)d_ws;

    // layout (bytes): wtb | offawb | qb | vb | pad | memb | attb
    // hidden (109,051,904) overlays offawb+qb+vb+pad exactly.
    const size_t SLAB = (size_t)NTOKP * 256 * 2;            // 27,262,976
    const size_t OASZ = (size_t)NTOKP * 384 * 2;            // 40,894,464
    const size_t HSZ  = (size_t)NTOKP * 1024 * 2;           // 109,051,904
    ushort* wtb    = (ushort*)(w8);                          // 1,572,864
    ushort* offawb = (ushort*)(w8 + 1572864);
    ushort* qb     = (ushort*)(w8 + 1572864 + OASZ);
    ushort* vb     = (ushort*)(w8 + 1572864 + OASZ + SLAB);
    ushort* memb   = (ushort*)(w8 + 1572864 + HSZ);
    ushort* attb   = (ushort*)(w8 + 1572864 + HSZ + SLAB);
    // total = 1,572,864 + 109,051,904 + 2*27,262,976 = 165,150,720 B (~157.5MB)

    // aliases after death:
    ushort* hidb   = offawb;   // FFN hidden (NTOKP x 1024), overlays offawb+qb+vb
    ushort* bufXb  = memb;     // LN1 out bf16 (memb dead after projs)
    ushort* projb  = vb;       // out-proj result (vb dead after deform; read by
                               // ln1 BEFORE ffn1 overwrites the region)
    ushort* ffn2b  = attb;     // FFN2 bf16 out (attb dead after out-proj)

    ushort* value_wt = wtb;            // [256][256]
    ushort* offaw_wt = wtb + 65536;    // [384][256]
    ushort* out_wt   = wtb + 163840;   // [256][256]
    ushort* lin1_wt  = wtb + 229376;   // [1024][256]
    ushort* lin2_wt  = wtb + 491520;   // [256][1024]

    const dim3 blk(256);
    const int n4 = NTOK * DMODEL / 4;                       // 3,403,264
    const int prep_total = 2 * n4 + 753664;
    prep_k<<<(prep_total + 255) / 256, blk, 0, stream>>>(
        src, pos, src2, mpos, qb, memb,
        value_w, off_w, aw_w, out_w, lin1_w, lin2_w, wtb, n4);

    const int mt = NTOKP / 128;   // 416
    // merged value(2) + offaw(3) projections, n-tile on x
    projs_k<<<dim3(5, mt), blk, 0, stream>>>(memb, qb, value_wt, offaw_wt,
                                             value_b, off_b, aw_b, vb, offawb);

    deform_k<<<dim3(NTOK / 8), blk, 0, stream>>>(vb, offawb, attb);

    // out proj: attb -> projb
    mgemm_k<<<dim3(2, mt), blk, 0, stream>>>(attb, out_wt, out_b, nullptr,
                                             nullptr, projb, NTOK, 256, 256, 0, 256);
    // x = LN(attn_proj + src) -> bufXb bf16
    ln_k<<<dim3(NTOK / 4), blk, 0, stream>>>(nullptr, projb, src, nullptr,
                                             ln_g, ln_b, nullptr, bufXb);

    // FFN single-chunk: hidden bf16 in hidb; FFN2 -> ffn2b bf16
    mgemm_k<<<dim3(8, mt), blk, 0, stream>>>(bufXb, lin1_wt, lin1_b, nullptr,
                                             nullptr, hidb, NTOK, DFFN, DMODEL, 1, DFFN);
    mgemm_k<<<dim3(2, mt), blk, 0, stream>>>(hidb, lin2_wt, lin2_b, nullptr,
                                             nullptr, ffn2b, NTOK, DMODEL, DFFN, 0, DMODEL);

    // out = LN(ffn + x) -> d_out f32
    ln_k<<<dim3(NTOK / 4), blk, 0, stream>>>(nullptr, ffn2b, nullptr, bufXb,
                                             ln_g, ln_b, outp, nullptr);
}

// Round 8
// 419.533 us; speedup vs baseline: 6.5055x; 1.0053x over previous
//
#include <hip/hip_runtime.h>
#include <math.h>

#define L_TOKN 13294
#define BATCHN 4
#define NTOK (BATCHN * L_TOKN)     // 53176
#define NTOKP 53248                // padded to multiple of 128
#define DMODEL 256
#define DFFN 1024

typedef __attribute__((ext_vector_type(8))) short short8;
typedef __attribute__((ext_vector_type(4))) float f32x4;
typedef __attribute__((ext_vector_type(2))) float f32x2;

__device__ __forceinline__ ushort f2b(float f) {
    uint u = __float_as_uint(f);
    u += 0x7fff + ((u >> 16) & 1);
    return (ushort)(u >> 16);
}
__device__ __forceinline__ float b2f(uint h) {
    return __uint_as_float(h << 16);
}

// ---------------------------------------------------------------------------
// prep: [0, 2*n4)  addcvt (qb = bf16(src+pos), memb = bf16(src2+mpos))
//       [2*n4, +753664) weight transpose/convert W[K][N] f32 -> Wt[N][K] bf16
// ---------------------------------------------------------------------------
__global__ __launch_bounds__(256) void prep_k(
    const float* __restrict__ s1, const float* __restrict__ p1,
    const float* __restrict__ s2, const float* __restrict__ p2,
    ushort* __restrict__ o1, ushort* __restrict__ o2,
    const float* __restrict__ w0, const float* __restrict__ w1,
    const float* __restrict__ w2, const float* __restrict__ w3,
    const float* __restrict__ w4, const float* __restrict__ w5,
    ushort* __restrict__ wtb, int n4)
{
    int i = blockIdx.x * 256 + threadIdx.x;
    if (i < 2 * n4) {
        const float* a; const float* b; ushort* o; int j;
        if (i < n4) { a = s1; b = p1; o = o1; j = i; }
        else        { a = s2; b = p2; o = o2; j = i - n4; }
        float4 va = ((const float4*)a)[j];
        float4 vb = ((const float4*)b)[j];
        ushort4 r;
        r.x = f2b(va.x + vb.x); r.y = f2b(va.y + vb.y);
        r.z = f2b(va.z + vb.z); r.w = f2b(va.w + vb.w);
        ((ushort4*)o)[j] = r;
        return;
    }
    int i2 = i - 2 * n4;
    const float* w; int Nd; size_t off; int j;
    if      (i2 < 65536)  { w = w0; Nd = 256;  off = 0;      j = i2; }
    else if (i2 < 131072) { w = w1; Nd = 256;  off = 65536;  j = i2 - 65536; }
    else if (i2 < 163840) { w = w2; Nd = 128;  off = 131072; j = i2 - 131072; }
    else if (i2 < 229376) { w = w3; Nd = 256;  off = 163840; j = i2 - 163840; }
    else if (i2 < 491520) { w = w4; Nd = 1024; off = 229376; j = i2 - 229376; }
    else if (i2 < 753664) { w = w5; Nd = 256;  off = 491520; j = i2 - 491520; }
    else return;
    int Kd = (i2 < 491520) ? 256 : 1024;
    int k = j / Nd, n = j - k * Nd;
    wtb[off + (size_t)n * Kd + k] = f2b(w[j]);
}

// ---------------------------------------------------------------------------
// bf16 MFMA GEMM core, 128x128 tile, BK=32, global_load_lds double-buffered
// with COUNTED vmcnt (T4): next tile's 4 loads/thread stay in flight across
// the barrier; vmcnt never drains to 0 in the main loop. Second barrier
// (lgkmcnt(0)) protects buffer overwrite; STAGE(ks+2) issues BEFORE the MFMA
// cluster so HBM latency hides under compute.
// A rows must be padded to tile multiple. Wt[N][K]. NOT safe in-place.
// ---------------------------------------------------------------------------
__device__ __forceinline__ void gemm_core(
    const ushort* __restrict__ A, const ushort* __restrict__ Wt,
    const float* __restrict__ bias, const float* __restrict__ bias2,
    float* __restrict__ Cf, ushort* __restrict__ Cb,
    int M, int N, int K, int relu, int nsplit, int m0, int n0)
{
    __shared__ ushort lds[16384];

    const int t  = threadIdx.x;
    const int wv = t >> 6, ln_ = t & 63;
    const int wr = wv >> 1, wc = wv & 1;
    const int fr = ln_ & 15;
    const int kg = ln_ >> 4;

    f32x4 acc[4][4];
    #pragma unroll
    for (int i = 0; i < 4; i++)
        #pragma unroll
        for (int j = 0; j < 4; j++) acc[i][j] = (f32x4)0.0f;

    int aoff[4], boff[4];
    #pragma unroll
    for (int i = 0; i < 4; i++) {
        aoff[i] = (wr * 64 + i * 16 + fr) * 32 + kg * 8;
        boff[i] = 4096 + (wc * 64 + i * 16 + fr) * 32 + kg * 8;
    }

// 4 loads/thread per STAGE (2 ii x {A,B}); vmcnt accounting relies on this.
#define STAGE(pbuf, k0) do {                                                       \
    _Pragma("unroll")                                                              \
    for (int ii = 0; ii < 2; ii++) {                                               \
        int c = (wv * 2 + ii) * 64 + ln_;                                          \
        int m = c >> 2, s = c & 3;                                                 \
        const ushort* sa = A  + (size_t)(m0 + m) * K + (k0) + s * 8;               \
        const ushort* sb = Wt + (size_t)(n0 + m) * K + (k0) + s * 8;               \
        __builtin_amdgcn_global_load_lds(                                          \
            (const __attribute__((address_space(1))) unsigned int*)sa,             \
            (__attribute__((address_space(3))) unsigned int*)&lds[(pbuf) * 8192 + (wv * 2 + ii) * 512], \
            16, 0, 0);                                                             \
        __builtin_amdgcn_global_load_lds(                                          \
            (const __attribute__((address_space(1))) unsigned int*)sb,             \
            (__attribute__((address_space(3))) unsigned int*)&lds[(pbuf) * 8192 + 4096 + (wv * 2 + ii) * 512], \
            16, 0, 0);                                                             \
    }                                                                              \
} while (0)

    const int nk = K >> 5;
    STAGE(0, 0);
    if (nk > 1) STAGE(1, 32);

    for (int ks = 0; ks < nk; ks++) {
        const int p = ks & 1;
        // own loads for buf p are the oldest 4; keep next tile's 4 in flight
        if (ks + 1 < nk) {
            asm volatile("s_waitcnt vmcnt(4)" ::: "memory");
        } else {
            asm volatile("s_waitcnt vmcnt(0)" ::: "memory");
        }
        __builtin_amdgcn_s_barrier();
        __builtin_amdgcn_sched_barrier(0);

        short8 af[4], bf[4];
        const int pb = p * 8192;
        #pragma unroll
        for (int i = 0; i < 4; i++) {
            af[i] = *(const short8*)&lds[pb + aoff[i]];
            bf[i] = *(const short8*)&lds[pb + boff[i]];
        }
        if (ks + 2 < nk) {
            // all waves done reading buf p -> safe to overwrite with step ks+2
            asm volatile("s_waitcnt lgkmcnt(0)" ::: "memory");
            __builtin_amdgcn_s_barrier();
            __builtin_amdgcn_sched_barrier(0);
            STAGE(p, (ks + 2) << 5);
        }
        #pragma unroll
        for (int i = 0; i < 4; i++)
            #pragma unroll
            for (int j = 0; j < 4; j++)
                acc[i][j] = __builtin_amdgcn_mfma_f32_16x16x32_bf16(af[i], bf[j], acc[i][j], 0, 0, 0);
    }
#undef STAGE

    #pragma unroll
    for (int i = 0; i < 4; i++) {
        #pragma unroll
        for (int j = 0; j < 4; j++) {
            int col = n0 + wc * 64 + j * 16 + fr;
            float bv = (col < nsplit) ? bias[col] : bias2[col - nsplit];
            #pragma unroll
            for (int e = 0; e < 4; e++) {
                int row = m0 + wr * 64 + i * 16 + kg * 4 + e;
                if (row >= M) continue;
                float v = acc[i][j][e] + bv;
                if (relu) v = fmaxf(v, 0.f);
                if (Cf) Cf[(size_t)row * N + col] = v;
                if (Cb) Cb[(size_t)row * N + col] = f2b(v);
            }
        }
    }
}

// generic GEMM: n-tile on blockIdx.x (L2 A-reuse), m-strip on blockIdx.y
__global__ __launch_bounds__(256) void mgemm_k(
    const ushort* __restrict__ A, const ushort* __restrict__ Wt,
    const float* __restrict__ bias, const float* __restrict__ bias2,
    float* __restrict__ Cf, ushort* __restrict__ Cb,
    int M, int N, int K, int relu, int nsplit)
{
    gemm_core(A, Wt, bias, bias2, Cf, Cb, M, N, K, relu, nsplit,
              blockIdx.y * 128, blockIdx.x * 128);
}

// merged value-proj (x<2) + offaw-proj (x>=2), both K=256
__global__ __launch_bounds__(256) void projs_k(
    const ushort* __restrict__ memb, const ushort* __restrict__ qb,
    const ushort* __restrict__ value_wt, const ushort* __restrict__ offaw_wt,
    const float* __restrict__ value_b, const float* __restrict__ off_b,
    const float* __restrict__ aw_b,
    ushort* __restrict__ vb, ushort* __restrict__ offawb)
{
    const int x = blockIdx.x;
    const int m0 = blockIdx.y * 128;
    const ushort* A; const ushort* Wt; const float* b1; const float* b2;
    ushort* Cb; int N, n0;
    if (x < 2) { A = memb; Wt = value_wt; b1 = value_b; b2 = value_b;
                 Cb = vb; N = 256; n0 = x * 128; }
    else       { A = qb;   Wt = offaw_wt; b1 = off_b;   b2 = aw_b;
                 Cb = offawb; N = 384; n0 = (x - 2) * 128; }
    gemm_core(A, Wt, b1, b2, nullptr, Cb, NTOK, N, 256, 0, 256, m0, n0);
}

// ---------------------------------------------------------------------------
// Deformable attention v3 (unchanged): barrier-free, 4 waves x 2 tokens.
// ---------------------------------------------------------------------------
__global__ __launch_bounds__(256) void deform_k(
    const ushort* __restrict__ Vb,      // bf16 (NTOK,256)
    const ushort* __restrict__ OFFAW,   // bf16 (NTOK,384)
    ushort* __restrict__ OUTb)          // bf16 (NTOK,256)
{
    __shared__ uint4 pw_idx[4][2][136];
    __shared__ uint2 pw_w[4][2][136];

    const int t = threadIdx.x;
    const int wv = t >> 6, lane = t & 63;
    const int tok0 = blockIdx.x * 8 + wv * 2;

    const int HWc[4] = {100, 50, 25, 13};
    const int STc[4] = {0, 10000, 12500, 13125};

    const int ppb = lane & 15;
    const int lvb = ppb >> 2;
    #pragma unroll
    for (int it = 0; it < 4; it++) {
        int tk = it >> 1;
        int h  = ((it & 1) << 2) + (lane >> 4);
        int row = tok0 + tk;
        int b = row / L_TOKN;
        int l = row - b * L_TOKN;
        int st_q, Wq;
        if      (l < 10000) { st_q = 0;     Wq = 100; }
        else if (l < 12500) { st_q = 10000; Wq = 50;  }
        else if (l < 13125) { st_q = 12500; Wq = 25;  }
        else                { st_q = 13125; Wq = 13;  }
        int li = l - st_q;
        int rowi = li / Wq;
        int coli = li - rowi * Wq;
        float rx = (coli + 0.5f) / (float)Wq;
        float ry = (rowi + 0.5f) / (float)Wq;

        const size_t rbase = (size_t)row * 384;
        uint oxy = *(const uint*)(OFFAW + rbase + h * 32 + ppb * 2);
        float ox = b2f(oxy & 0xffffu);
        float oy = b2f(oxy >> 16);
        float lg = b2f((uint)OFFAW[rbase + 256 + h * 16 + ppb]);
        float mx = lg;
        #pragma unroll
        for (int o = 8; o; o >>= 1) mx = fmaxf(mx, __shfl_xor(mx, o));
        float ex = __expf(lg - mx);
        float sm = ex;
        #pragma unroll
        for (int o = 8; o; o >>= 1) sm += __shfl_xor(sm, o);
        float aw = ex / sm;

        int Wl = HWc[lvb], stl = STc[lvb];
        float Wlf = (float)Wl;
        float x = (rx + ox / Wlf) * Wlf - 0.5f;
        float y = (ry + oy / Wlf) * Wlf - 0.5f;
        float x0f = floorf(x), y0f = floorf(y);
        float wx1 = x - x0f, wy1 = y - y0f;
        float wx0 = 1.f - wx1, wy0 = 1.f - wy1;
        int x0 = (int)x0f, y0 = (int)y0f;
        bool vx0 = (x0 >= 0) & (x0 < Wl);
        bool vx1 = (x0 + 1 >= 0) & (x0 + 1 < Wl);
        bool vy0 = (y0 >= 0) & (y0 < Wl);
        bool vy1 = (y0 + 1 >= 0) & (y0 + 1 < Wl);
        int cx0 = min(max(x0, 0), Wl - 1), cx1 = min(max(x0 + 1, 0), Wl - 1);
        int cy0 = min(max(y0, 0), Wl - 1), cy1 = min(max(y0 + 1, 0), Wl - 1);
        uint gb = (uint)(b * L_TOKN + stl);
        uint4 o4;
        o4.x = (gb + cy0 * Wl + cx0) * 512u;
        o4.y = (gb + cy0 * Wl + cx1) * 512u;
        o4.z = (gb + cy1 * Wl + cx0) * 512u;
        o4.w = (gb + cy1 * Wl + cx1) * 512u;
        float w00 = wx0 * wy0 * aw * (float)(vx0 & vy0);
        float w10 = wx1 * wy0 * aw * (float)(vx1 & vy0);
        float w01 = wx0 * wy1 * aw * (float)(vx0 & vy1);
        float w11 = wx1 * wy1 * aw * (float)(vx1 & vy1);
        uint2 wp;
        wp.x = (uint)f2b(w00) | ((uint)f2b(w10) << 16);
        wp.y = (uint)f2b(w01) | ((uint)f2b(w11) << 16);
        pw_idx[wv][tk][h * 17 + ppb] = o4;
        pw_w[wv][tk][h * 17 + ppb]   = wp;
    }

    asm volatile("s_waitcnt lgkmcnt(0)" ::: "memory");
    __builtin_amdgcn_sched_barrier(0);

    const int tk = lane >> 5;
    const int h  = (lane >> 2) & 7;
    const int dq = lane & 3;
    const int row = tok0 + tk;
    const uint choff = (uint)(h * 64 + dq * 16);
    const char* __restrict__ vbase = (const char*)Vb;

    f32x2 acc2[4];
    #pragma unroll
    for (int k = 0; k < 4; k++) acc2[k] = (f32x2)0.0f;

    #pragma unroll 8
    for (int pq = 0; pq < 16; pq++) {
        uint4 o4 = pw_idx[wv][tk][h * 17 + pq];
        uint2 wp = pw_w[wv][tk][h * 17 + pq];
        float w00 = b2f(wp.x & 0xffffu);
        float w10 = __uint_as_float(wp.x & 0xffff0000u);
        float w01 = b2f(wp.y & 0xffffu);
        float w11 = __uint_as_float(wp.y & 0xffff0000u);
        uint4 v00 = *(const uint4*)(vbase + o4.x + choff);
        uint4 v10 = *(const uint4*)(vbase + o4.y + choff);
        uint4 v01 = *(const uint4*)(vbase + o4.z + choff);
        uint4 v11 = *(const uint4*)(vbase + o4.w + choff);
        const uint* p00 = (const uint*)&v00;
        const uint* p10 = (const uint*)&v10;
        const uint* p01 = (const uint*)&v01;
        const uint* p11 = (const uint*)&v11;
        #pragma unroll
        for (int k = 0; k < 4; k++) {
            f32x2 a0, a1, a2, a3;
            a0.x = __uint_as_float(p00[k] << 16); a0.y = __uint_as_float(p00[k] & 0xffff0000u);
            a1.x = __uint_as_float(p10[k] << 16); a1.y = __uint_as_float(p10[k] & 0xffff0000u);
            a2.x = __uint_as_float(p01[k] << 16); a2.y = __uint_as_float(p01[k] & 0xffff0000u);
            a3.x = __uint_as_float(p11[k] << 16); a3.y = __uint_as_float(p11[k] & 0xffff0000u);
            acc2[k] += a0 * w00 + a1 * w10 + a2 * w01 + a3 * w11;
        }
    }
    ushort4 olo, ohi;
    olo.x = f2b(acc2[0].x); olo.y = f2b(acc2[0].y);
    olo.z = f2b(acc2[1].x); olo.w = f2b(acc2[1].y);
    ohi.x = f2b(acc2[2].x); ohi.y = f2b(acc2[2].y);
    ohi.z = f2b(acc2[3].x); ohi.w = f2b(acc2[3].y);
    ushort* op = OUTb + (size_t)row * 256 + h * 32 + dq * 8;
    *(ushort4*)op = olo;
    *(ushort4*)(op + 4) = ohi;
}

// ---------------------------------------------------------------------------
// LayerNorm(256), one wave per row.
// ---------------------------------------------------------------------------
__global__ __launch_bounds__(256) void ln_k(
    const float* __restrict__ af, const ushort* __restrict__ ab,
    const float* __restrict__ bf2, const ushort* __restrict__ bb2,
    const float* __restrict__ g, const float* __restrict__ bta,
    float* __restrict__ of, ushort* __restrict__ ob)
{
    const int r = blockIdx.x * 4 + (threadIdx.x >> 6);
    const int lane = threadIdx.x & 63;
    float4 v;
    if (af) {
        v = *((const float4*)(af + (size_t)r * 256) + lane);
    } else {
        ushort4 u = *((const ushort4*)(ab + (size_t)r * 256) + lane);
        v.x = b2f(u.x); v.y = b2f(u.y); v.z = b2f(u.z); v.w = b2f(u.w);
    }
    if (bf2) {
        float4 v2 = *((const float4*)(bf2 + (size_t)r * 256) + lane);
        v.x += v2.x; v.y += v2.y; v.z += v2.z; v.w += v2.w;
    } else if (bb2) {
        ushort4 u = *((const ushort4*)(bb2 + (size_t)r * 256) + lane);
        v.x += b2f(u.x); v.y += b2f(u.y); v.z += b2f(u.z); v.w += b2f(u.w);
    }
    float s = v.x + v.y + v.z + v.w;
    #pragma unroll
    for (int o = 32; o; o >>= 1) s += __shfl_xor(s, o);
    float mu = s * (1.f / 256.f);
    float4 d; d.x = v.x - mu; d.y = v.y - mu; d.z = v.z - mu; d.w = v.w - mu;
    float s2 = d.x * d.x + d.y * d.y + d.z * d.z + d.w * d.w;
    #pragma unroll
    for (int o = 32; o; o >>= 1) s2 += __shfl_xor(s2, o);
    float rstd = rsqrtf(s2 * (1.f / 256.f) + 1e-5f);
    float4 gg = ((const float4*)g)[lane];
    float4 bb = ((const float4*)bta)[lane];
    float4 out;
    out.x = d.x * rstd * gg.x + bb.x;
    out.y = d.y * rstd * gg.y + bb.y;
    out.z = d.z * rstd * gg.z + bb.z;
    out.w = d.w * rstd * gg.w + bb.w;
    if (of) *((float4*)(of + (size_t)r * 256) + lane) = out;
    if (ob) {
        ushort4 o4;
        o4.x = f2b(out.x); o4.y = f2b(out.y); o4.z = f2b(out.z); o4.w = f2b(out.w);
        *((ushort4*)(ob + (size_t)r * 256) + lane) = o4;
    }
}

// ---------------------------------------------------------------------------
extern "C" void kernel_launch(void* const* d_in, const int* in_sizes, int n_in,
                              void* d_out, int out_size, void* d_ws, size_t ws_size,
                              hipStream_t stream)
{
    const float* src     = (const float*)d_in[0];
    const float* src2    = (const float*)d_in[1];
    const float* pos     = (const float*)d_in[2];
    const float* mpos    = (const float*)d_in[3];
    const float* value_w = (const float*)d_in[4];
    const float* value_b = (const float*)d_in[5];
    const float* off_w   = (const float*)d_in[6];
    const float* off_b   = (const float*)d_in[7];
    const float* aw_w    = (const float*)d_in[8];
    const float* aw_b    = (const float*)d_in[9];
    const float* out_w   = (const float*)d_in[10];
    const float* out_b   = (const float*)d_in[11];
    const float* ln_g    = (const float*)d_in[12];
    const float* ln_b    = (const float*)d_in[13];
    const float* lin1_w  = (const float*)d_in[14];
    const float* lin1_b  = (const float*)d_in[15];
    const float* lin2_w  = (const float*)d_in[16];
    const float* lin2_b  = (const float*)d_in[17];

    float* outp = (float*)d_out;
    char*  w8   = (char*)d_ws;

    // layout (bytes): wtb | offawb | qb | vb | pad | memb | attb
    // hidden (109,051,904) overlays offawb+qb+vb+pad exactly.
    const size_t SLAB = (size_t)NTOKP * 256 * 2;            // 27,262,976
    const size_t OASZ = (size_t)NTOKP * 384 * 2;            // 40,894,464
    const size_t HSZ  = (size_t)NTOKP * 1024 * 2;           // 109,051,904
    ushort* wtb    = (ushort*)(w8);                          // 1,572,864
    ushort* offawb = (ushort*)(w8 + 1572864);
    ushort* qb     = (ushort*)(w8 + 1572864 + OASZ);
    ushort* vb     = (ushort*)(w8 + 1572864 + OASZ + SLAB);
    ushort* memb   = (ushort*)(w8 + 1572864 + HSZ);
    ushort* attb   = (ushort*)(w8 + 1572864 + HSZ + SLAB);

    // aliases after death:
    ushort* hidb   = offawb;   // FFN hidden (NTOKP x 1024), overlays offawb+qb+vb
    ushort* bufXb  = memb;     // LN1 out bf16 (memb dead after projs)
    ushort* projb  = vb;       // out-proj result (vb dead after deform)
    ushort* ffn2b  = attb;     // FFN2 bf16 out (attb dead after out-proj)

    ushort* value_wt = wtb;            // [256][256]
    ushort* offaw_wt = wtb + 65536;    // [384][256]
    ushort* out_wt   = wtb + 163840;   // [256][256]
    ushort* lin1_wt  = wtb + 229376;   // [1024][256]
    ushort* lin2_wt  = wtb + 491520;   // [256][1024]

    const dim3 blk(256);
    const int n4 = NTOK * DMODEL / 4;                       // 3,403,264
    const int prep_total = 2 * n4 + 753664;
    prep_k<<<(prep_total + 255) / 256, blk, 0, stream>>>(
        src, pos, src2, mpos, qb, memb,
        value_w, off_w, aw_w, out_w, lin1_w, lin2_w, wtb, n4);

    const int mt = NTOKP / 128;   // 416
    // merged value(2) + offaw(3) projections, n-tile on x
    projs_k<<<dim3(5, mt), blk, 0, stream>>>(memb, qb, value_wt, offaw_wt,
                                             value_b, off_b, aw_b, vb, offawb);

    deform_k<<<dim3(NTOK / 8), blk, 0, stream>>>(vb, offawb, attb);

    // out proj: attb -> projb
    mgemm_k<<<dim3(2, mt), blk, 0, stream>>>(attb, out_wt, out_b, nullptr,
                                             nullptr, projb, NTOK, 256, 256, 0, 256);
    // x = LN(attn_proj + src) -> bufXb bf16
    ln_k<<<dim3(NTOK / 4), blk, 0, stream>>>(nullptr, projb, src, nullptr,
                                             ln_g, ln_b, nullptr, bufXb);

    // FFN single-chunk: hidden bf16 in hidb; FFN2 -> ffn2b bf16
    mgemm_k<<<dim3(8, mt), blk, 0, stream>>>(bufXb, lin1_wt, lin1_b, nullptr,
                                             nullptr, hidb, NTOK, DFFN, DMODEL, 1, DFFN);
    mgemm_k<<<dim3(2, mt), blk, 0, stream>>>(hidb, lin2_wt, lin2_b, nullptr,
                                             nullptr, ffn2b, NTOK, DMODEL, DFFN, 0, DMODEL);

    // out = LN(ffn + x) -> d_out f32
    ln_k<<<dim3(NTOK / 4), blk, 0, stream>>>(nullptr, ffn2b, nullptr, bufXb,
                                             ln_g, ln_b, outp, nullptr);
}